// Round 1
// baseline (1078.558 us; speedup 1.0000x reference)
//
#include <hip/hip_runtime.h>

typedef unsigned short u16;
typedef unsigned int u32;
typedef __bf16 bf16x8 __attribute__((ext_vector_type(8)));
typedef float f32x4 __attribute__((ext_vector_type(4)));

#define NHEAD 28
#define NKVH 4
#define HD 128
#define NB 2
#define NS 2048
#define NTOK 4096
#define HIDDEN_DIM 3584
#define QKVW 4608
#define QSZ 3584
#define KOFF 3584
#define VOFF 4096
#define QSCALE 0.08838834764831845f

__device__ __forceinline__ float bf2f(u16 u) {
  u32 x = ((u32)u) << 16; float f; __builtin_memcpy(&f, &x, 4); return f;
}
__device__ __forceinline__ u16 f2bf(float f) {
  u32 x; __builtin_memcpy(&x, &f, 4);
  x += 0x7FFFu + ((x >> 16) & 1u);
  return (u16)(x >> 16);
}
__device__ __forceinline__ void async16(const void* g, void* lds) {
  __builtin_amdgcn_global_load_lds((const __attribute__((address_space(1))) void*)g,
                                   (__attribute__((address_space(3))) void*)lds,
                                   16, 0, 0);
}

// ---------------- elementwise f32 -> bf16 cast (4 elems/thread) ----------------
__global__ void cast_f32_bf16(const float* __restrict__ in, u16* __restrict__ out) {
  int i = (blockIdx.x * 256 + threadIdx.x) * 4;
  float4 v = *(const float4*)(in + i);
  u32 p0 = (u32)f2bf(v.x) | ((u32)f2bf(v.y) << 16);
  u32 p1 = (u32)f2bf(v.z) | ((u32)f2bf(v.w) << 16);
  uint2 r; r.x = p0; r.y = p1;
  *(uint2*)(out + i) = r;
}

// ------------- tiled transpose + cast: in f32 [R][C] -> out bf16 [C][R] --------
__global__ void transpose_cast(const float* __restrict__ in, u16* __restrict__ out,
                               int R, int C) {
  __shared__ float tile[32][33];
  int tx = threadIdx.x & 31, ty = threadIdx.x >> 5;   // 32 x 8
  int c0 = blockIdx.x * 32, r0 = blockIdx.y * 32;
#pragma unroll
  for (int i = 0; i < 32; i += 8)
    tile[ty + i][tx] = in[(size_t)(r0 + ty + i) * C + c0 + tx];
  __syncthreads();
#pragma unroll
  for (int i = 0; i < 32; i += 8)
    out[(size_t)(c0 + ty + i) * R + r0 + tx] = f2bf(tile[tx][ty + i]);
}

// ---------------- rope cos/sin table: [NTOK][64] each --------------------------
__global__ void rope_table(const int* __restrict__ positions,
                           float* __restrict__ cs, float* __restrict__ sn) {
  int idx = blockIdx.x * 256 + threadIdx.x;   // NTOK*64
  int t = idx >> 6, i = idx & 63;
  float p = (float)positions[t];
  // inv_freq = theta^(-i/64), theta=1e6 ; ln(1e6)=13.815510557964274
  float inv = expf(-(float)i * (13.815510557964274f / 64.f));
  float a = p * inv;
  cs[idx] = cosf(a);
  sn[idx] = sinf(a);
}

// ---------------- in-place RoPE on qkv (q scaled by D^-0.5) --------------------
__global__ void rope_kernel(u16* __restrict__ qkv, const float* __restrict__ cs,
                            const float* __restrict__ sn) {
  int w = threadIdx.x >> 6, l = threadIdx.x & 63;
  int rid = blockIdx.x * 4 + w;          // NTOK * 32 head-rows
  int t = rid >> 5, hh = rid & 31;
  size_t base = (size_t)t * QKVW + (hh < NHEAD ? hh * HD : KOFF + (hh - NHEAD) * HD);
  float x1 = bf2f(qkv[base + l]), x2 = bf2f(qkv[base + l + 64]);
  float c = cs[t * 64 + l], s = sn[t * 64 + l];
  float y1 = x1 * c - x2 * s;
  float y2 = x2 * c + x1 * s;
  if (hh < NHEAD) { y1 *= QSCALE; y2 *= QSCALE; }
  qkv[base + l] = f2bf(y1);
  qkv[base + l + 64] = f2bf(y2);
}

// ---------------- 128x128 MFMA GEMM, A [M][K] bf16, Bt [N][K] bf16 -------------
// m97 structure: BK=32, 4 waves (2x2 of 64x64), global_load_lds w=16, 16 MFMA/K-step
template <bool OUT_BF16, bool HAS_BIAS>
__global__ __launch_bounds__(256) void gemm128(
    const u16* __restrict__ A, const u16* __restrict__ Bt,
    const float* __restrict__ bias, u16* __restrict__ outb,
    float* __restrict__ outf, int M, int N, int K) {
  __shared__ __align__(16) u16 As[128 * 32];
  __shared__ __align__(16) u16 Bs[128 * 32];
  const int tid = threadIdx.x;
  const int l = tid & 63, w = tid >> 6;
  const int nbx = N >> 7;
  const int bx = blockIdx.x % nbx, by = blockIdx.x / nbx;
  const int row0 = by * 128, col0 = bx * 128;
  const int wr = w >> 1, wc = w & 1;
  f32x4 acc[4][4] = {};
  const int NK = K >> 5;

  for (int kt = 0; kt < NK; ++kt) {
    const int k0 = kt * 32;
    __syncthreads();   // previous iteration's LDS reads done
#pragma unroll
    for (int p = 0; p < 2; ++p) {
      const int cidx = p * 4 + w;                    // 8 chunks of 1KB
      const int r = cidx * 16 + (l >> 2);            // tile row
      const int c8 = (l & 3) * 8;                    // k element offset
      async16(A + (size_t)(row0 + r) * K + k0 + c8, (char*)As + cidx * 1024);
      async16(Bt + (size_t)(col0 + r) * K + k0 + c8, (char*)Bs + cidx * 1024);
    }
    asm volatile("s_waitcnt vmcnt(0)" ::: "memory");
    __syncthreads();   // staged tile visible to all waves

    bf16x8 af[4], bfr[4];
#pragma unroll
    for (int m = 0; m < 4; ++m)
      af[m] = *(const bf16x8*)((const char*)As + (wr * 64 + m * 16 + (l & 15)) * 64 + (l >> 4) * 16);
#pragma unroll
    for (int n = 0; n < 4; ++n)
      bfr[n] = *(const bf16x8*)((const char*)Bs + (wc * 64 + n * 16 + (l & 15)) * 64 + (l >> 4) * 16);
#pragma unroll
    for (int m = 0; m < 4; ++m)
#pragma unroll
      for (int n = 0; n < 4; ++n)
        acc[m][n] = __builtin_amdgcn_mfma_f32_16x16x32_bf16(af[m], bfr[n], acc[m][n], 0, 0, 0);
  }

  // epilogue: C row = (l>>4)*4 + j, col = l&15  [verified m89/m91 mapping]
#pragma unroll
  for (int m = 0; m < 4; ++m) {
    const int row = row0 + wr * 64 + m * 16 + (l >> 4) * 4;
#pragma unroll
    for (int n = 0; n < 4; ++n) {
      const int col = col0 + wc * 64 + n * 16 + (l & 15);
      float bb = HAS_BIAS ? bias[col] : 0.f;
#pragma unroll
      for (int j = 0; j < 4; ++j) {
        float v = acc[m][n][j] + bb;
        if (OUT_BF16) outb[(size_t)(row + j) * N + col] = f2bf(v);
        else          outf[(size_t)(row + j) * N + col] = v;
      }
    }
  }
}

// ---------------- causal GQA flash attention -----------------------------------
// block: 4 waves, QBLK=64 (16 q-rows/wave), KVBLK=64, online softmax
__global__ __launch_bounds__(256) void attn_kernel(const u16* __restrict__ qkv,
                                                   u16* __restrict__ Oh) {
  __shared__ __align__(16) u16 Ks[64 * 128];   // [key][d], XOR-swizzled, 16KB
  __shared__ __align__(16) u16 Vt[128 * 64];   // [d][key], XOR-swizzled, 16KB
  __shared__ __align__(16) u16 Pl[4 * 16 * 64];// per-wave P, 8KB
  const int tid = threadIdx.x, l = tid & 63, w = tid >> 6;
  const int bidx = blockIdx.x;
  const int qt = 31 - (bidx & 31);             // heavy tiles first
  const int bh = bidx >> 5;
  const int h = bh % NHEAD, b = bh / NHEAD;
  const int kvh = h / 7;
  const int q0 = qt * 64;

  // Q fragments in registers (A-frag: row = l&15, k = (l>>4)*8.. per 32-k step)
  const int qrow = q0 + w * 16 + (l & 15);
  const size_t qbase = (size_t)(b * NS + qrow) * QKVW + h * HD;
  bf16x8 qf[4];
#pragma unroll
  for (int ks = 0; ks < 4; ++ks)
    qf[ks] = *(const bf16x8*)(qkv + qbase + ks * 32 + (l >> 4) * 8);

  f32x4 oacc[8] = {};
  float mrun[4], lrun[4];
#pragma unroll
  for (int j = 0; j < 4; ++j) { mrun[j] = -1e30f; lrun[j] = 0.f; }

  const int nkv = qt + 1;
  for (int kvt = 0; kvt < nkv; ++kvt) {
    const int kv0 = kvt * 64;
    __syncthreads();
    // ---- stage K tile [64][128] with swizzle (16B chunks) ----
#pragma unroll
    for (int p = 0; p < 4; ++p) {
      const int c = tid + p * 256;
      const int row = c >> 4, cc = c & 15;
      float4 v = *(const float4*)(qkv + (size_t)(b * NS + kv0 + row) * QKVW + KOFF + kvh * HD + cc * 8);
      *(float4*)((char*)Ks + row * 256 + ((cc * 16) ^ ((row & 7) << 4))) = v;
    }
    // ---- stage V transposed: Vt[d][key], swizzled ----
#pragma unroll
    for (int p = 0; p < 4; ++p) {
      const int c = tid + p * 256;
      const int row = c >> 4, cc = c & 15;     // key=row, d0=cc*8
      uint4 v = *(const uint4*)(qkv + (size_t)(b * NS + kv0 + row) * QKVW + VOFF + kvh * HD + cc * 8);
      u32 vv[4] = {v.x, v.y, v.z, v.w};
#pragma unroll
      for (int e = 0; e < 8; ++e) {
        const int d = cc * 8 + e;
        u16 val = (u16)(vv[e >> 1] >> ((e & 1) * 16));
        *(u16*)((char*)Vt + d * 128 + ((row * 2) ^ ((d & 7) << 4))) = val;
      }
    }
    __syncthreads();

    // ---- QK^T: 16 MFMA -> scores 16x64 per wave ----
    f32x4 sacc[4] = {};
#pragma unroll
    for (int n = 0; n < 4; ++n) {
      const int key = n * 16 + (l & 15);
#pragma unroll
      for (int ks = 0; ks < 4; ++ks) {
        bf16x8 kf = *(const bf16x8*)((const char*)Ks + key * 256 +
                                     ((ks * 64 + (l >> 4) * 16) ^ ((key & 7) << 4)));
        sacc[n] = __builtin_amdgcn_mfma_f32_16x16x32_bf16(qf[ks], kf, sacc[n], 0, 0, 0);
      }
    }
    // ---- causal mask (only the diagonal tile) ----
    if (kvt == qt) {
#pragma unroll
      for (int n = 0; n < 4; ++n) {
        const int key_g = kv0 + n * 16 + (l & 15);
#pragma unroll
        for (int j = 0; j < 4; ++j) {
          const int q_g = q0 + w * 16 + (l >> 4) * 4 + j;
          if (key_g > q_g) sacc[n][j] = -1e30f;
        }
      }
    }
    // ---- online softmax (16-lane-group shuffle reduce) ----
#pragma unroll
    for (int j = 0; j < 4; ++j) {
      float mx = fmaxf(fmaxf(sacc[0][j], sacc[1][j]), fmaxf(sacc[2][j], sacc[3][j]));
#pragma unroll
      for (int mk = 1; mk < 16; mk <<= 1) mx = fmaxf(mx, __shfl_xor(mx, mk, 64));
      const float mnew = fmaxf(mrun[j], mx);
      const float scale = __expf(mrun[j] - mnew);
      mrun[j] = mnew;
      float sum = 0.f;
#pragma unroll
      for (int n = 0; n < 4; ++n) {
        float p = __expf(sacc[n][j] - mnew);
        sacc[n][j] = p;
        sum += p;
      }
#pragma unroll
      for (int mk = 1; mk < 16; mk <<= 1) sum += __shfl_xor(sum, mk, 64);
      lrun[j] = lrun[j] * scale + sum;
#pragma unroll
      for (int dt = 0; dt < 8; ++dt) oacc[dt][j] *= scale;
    }
    // ---- P -> per-wave LDS (bf16), then PV: 16 MFMA ----
#pragma unroll
    for (int n = 0; n < 4; ++n)
#pragma unroll
      for (int j = 0; j < 4; ++j)
        Pl[w * 1024 + ((l >> 4) * 4 + j) * 64 + n * 16 + (l & 15)] = f2bf(sacc[n][j]);
    asm volatile("s_waitcnt lgkmcnt(0)" ::: "memory");
#pragma unroll
    for (int ks = 0; ks < 2; ++ks) {
      bf16x8 pf = *(const bf16x8*)(Pl + w * 1024 + (l & 15) * 64 + ks * 32 + (l >> 4) * 8);
#pragma unroll
      for (int dt = 0; dt < 8; ++dt) {
        const int d = dt * 16 + (l & 15);
        bf16x8 vf = *(const bf16x8*)((const char*)Vt + d * 128 +
                                     ((ks * 64 + (l >> 4) * 16) ^ ((d & 7) << 4)));
        oacc[dt] = __builtin_amdgcn_mfma_f32_16x16x32_bf16(pf, vf, oacc[dt], 0, 0, 0);
      }
    }
  }

  // ---- epilogue: O /= l, write bf16 [token][h*128+d] ----
#pragma unroll
  for (int j = 0; j < 4; ++j) {
    const float inv = 1.f / lrun[j];
    const int row = q0 + w * 16 + (l >> 4) * 4 + j;
    const size_t obase = (size_t)(b * NS + row) * QSZ + h * HD;
#pragma unroll
    for (int dt = 0; dt < 8; ++dt)
      Oh[obase + dt * 16 + (l & 15)] = f2bf(oacc[dt][j] * inv);
  }
}

// -------------------------------------------------------------------------------
extern "C" void kernel_launch(void* const* d_in, const int* in_sizes, int n_in,
                              void* d_out, int out_size, void* d_ws, size_t ws_size,
                              hipStream_t stream) {
  const int* positions = (const int*)d_in[0];
  const float* hidden = (const float*)d_in[1];
  const float* w_qkv = (const float*)d_in[2];
  const float* b_qkv = (const float*)d_in[3];
  const float* w_o = (const float*)d_in[4];
  float* out = (float*)d_out;

  char* ws = (char*)d_ws;
  const size_t XB_OFF = 0;                           // 29,360,128 B (later reused by WoT)
  const size_t WQT_OFF = 29360128;                   // 33,030,144 B (later reused by Oh)
  const size_t QKV_OFF = WQT_OFF + 33030144;         // 37,748,736 B
  const size_t CS_OFF = QKV_OFF + 37748736;          // 1,048,576 B
  const size_t SN_OFF = CS_OFF + 1048576;            // 1,048,576 B
  const size_t WS_NEED = SN_OFF + 1048576;           // ~102.2 MB
  if (ws_size < WS_NEED) return;

  u16* Xb = (u16*)(ws + XB_OFF);
  u16* WoT = (u16*)(ws + XB_OFF);    // alias: used after GEMM1 consumed Xb
  u16* WqT = (u16*)(ws + WQT_OFF);
  u16* Oh = (u16*)(ws + WQT_OFF);    // alias: used after GEMM1 consumed WqT
  u16* qkvb = (u16*)(ws + QKV_OFF);
  float* cs = (float*)(ws + CS_OFF);
  float* sn = (float*)(ws + SN_OFF);

  // 1. casts / transposes / rope table
  cast_f32_bf16<<<14336, 256, 0, stream>>>(hidden, Xb);                    // 14,680,064 elems
  transpose_cast<<<dim3(QKVW / 32, HIDDEN_DIM / 32), 256, 0, stream>>>(w_qkv, WqT, HIDDEN_DIM, QKVW);
  rope_table<<<(NTOK * 64) / 256, 256, 0, stream>>>(positions, cs, sn);

  // 2. QKV projection (+bias), bf16 out
  gemm128<true, true><<<(QKVW / 128) * (NTOK / 128), 256, 0, stream>>>(
      Xb, WqT, b_qkv, qkvb, nullptr, NTOK, QKVW, HIDDEN_DIM);

  // 3. RoPE in place on q,k (q scaled)
  rope_kernel<<<(NTOK * 32) / 4, 256, 0, stream>>>(qkvb, cs, sn);

  // 4. w_o transpose (reuses Xb space — after GEMM1 in stream order)
  transpose_cast<<<dim3(HIDDEN_DIM / 32, QSZ / 32), 256, 0, stream>>>(w_o, WoT, QSZ, HIDDEN_DIM);

  // 5. flash attention -> Oh bf16 [token][h*128+d]
  attn_kernel<<<NB * NHEAD * (NS / 64), 256, 0, stream>>>(qkvb, Oh);

  // 6. output projection, f32 out
  gemm128<false, false><<<(HIDDEN_DIM / 128) * (NTOK / 128), 256, 0, stream>>>(
      Oh, WoT, nullptr, nullptr, out, NTOK, HIDDEN_DIM, QSZ);
}

// Round 2
// 793.015 us; speedup vs baseline: 1.3601x; 1.3601x over previous
//
#include <hip/hip_runtime.h>

typedef unsigned short u16;
typedef unsigned int u32;
typedef __bf16 bf16x8 __attribute__((ext_vector_type(8)));
typedef float f32x4 __attribute__((ext_vector_type(4)));

#define NHEAD 28
#define NKVH 4
#define HD 128
#define NB 2
#define NS 2048
#define NTOK 4096
#define HIDDEN_DIM 3584
#define QKVW 4608
#define QSZ 3584
#define KOFF 3584
#define VOFF 4096
#define QSCALE 0.08838834764831845f

__device__ __forceinline__ float bf2f(u16 u) {
  u32 x = ((u32)u) << 16; float f; __builtin_memcpy(&f, &x, 4); return f;
}
__device__ __forceinline__ u16 f2bf(float f) {
  u32 x; __builtin_memcpy(&x, &f, 4);
  x += 0x7FFFu + ((x >> 16) & 1u);
  return (u16)(x >> 16);
}
__device__ __forceinline__ void async16(const void* g, void* lds) {
  __builtin_amdgcn_global_load_lds((const __attribute__((address_space(1))) void*)g,
                                   (__attribute__((address_space(3))) void*)lds,
                                   16, 0, 0);
}

// ---------------- elementwise f32 -> bf16 cast (4 elems/thread) ----------------
__global__ void cast_f32_bf16(const float* __restrict__ in, u16* __restrict__ out) {
  int i = (blockIdx.x * 256 + threadIdx.x) * 4;
  float4 v = *(const float4*)(in + i);
  u32 p0 = (u32)f2bf(v.x) | ((u32)f2bf(v.y) << 16);
  u32 p1 = (u32)f2bf(v.z) | ((u32)f2bf(v.w) << 16);
  uint2 r; r.x = p0; r.y = p1;
  *(uint2*)(out + i) = r;
}

// ------------- tiled transpose + cast: in f32 [R][C] -> out bf16 [C][R] --------
__global__ void transpose_cast(const float* __restrict__ in, u16* __restrict__ out,
                               int R, int C) {
  __shared__ float tile[32][33];
  int tx = threadIdx.x & 31, ty = threadIdx.x >> 5;   // 32 x 8
  int c0 = blockIdx.x * 32, r0 = blockIdx.y * 32;
#pragma unroll
  for (int i = 0; i < 32; i += 8)
    tile[ty + i][tx] = in[(size_t)(r0 + ty + i) * C + c0 + tx];
  __syncthreads();
#pragma unroll
  for (int i = 0; i < 32; i += 8)
    out[(size_t)(c0 + ty + i) * R + r0 + tx] = f2bf(tile[tx][ty + i]);
}

// ---------------- rope cos/sin table: [NTOK][64] each --------------------------
__global__ void rope_table(const int* __restrict__ positions,
                           float* __restrict__ cs, float* __restrict__ sn) {
  int idx = blockIdx.x * 256 + threadIdx.x;   // NTOK*64
  int t = idx >> 6, i = idx & 63;
  float p = (float)positions[t];
  float inv = expf(-(float)i * (13.815510557964274f / 64.f));
  float a = p * inv;
  cs[idx] = cosf(a);
  sn[idx] = sinf(a);
}

// ---------------- in-place RoPE on qkv (q scaled by D^-0.5) --------------------
__global__ void rope_kernel(u16* __restrict__ qkv, const float* __restrict__ cs,
                            const float* __restrict__ sn) {
  int w = threadIdx.x >> 6, l = threadIdx.x & 63;
  int rid = blockIdx.x * 4 + w;          // NTOK * 32 head-rows
  int t = rid >> 5, hh = rid & 31;
  size_t base = (size_t)t * QKVW + (hh < NHEAD ? hh * HD : KOFF + (hh - NHEAD) * HD);
  float x1 = bf2f(qkv[base + l]), x2 = bf2f(qkv[base + l + 64]);
  float c = cs[t * 64 + l], s = sn[t * 64 + l];
  float y1 = x1 * c - x2 * s;
  float y2 = x2 * c + x1 * s;
  if (hh < NHEAD) { y1 *= QSCALE; y2 *= QSCALE; }
  qkv[base + l] = f2bf(y1);
  qkv[base + l + 64] = f2bf(y2);
}

// ---------------- 128x128 MFMA GEMM, A [M][K] bf16, Bt [N][K] bf16 -------------
// m97 structure. VSPLIT: tiles in the V column range write TRANSPOSED to vtg
// (layout [(b*NKVH+kvh)*HD+d][NS]) instead of the row-major output.
template <bool OUT_BF16, bool HAS_BIAS, bool VSPLIT>
__global__ __launch_bounds__(256) void gemm128(
    const u16* __restrict__ A, const u16* __restrict__ Bt,
    const float* __restrict__ bias, u16* __restrict__ outb,
    float* __restrict__ outf, u16* __restrict__ vtg, int M, int N, int K) {
  __shared__ __align__(16) u16 As[128 * 32];
  __shared__ __align__(16) u16 Bs[128 * 32];
  const int tid = threadIdx.x;
  const int l = tid & 63, w = tid >> 6;
  const int nbx = N >> 7;
  const int bx = blockIdx.x % nbx, by = blockIdx.x / nbx;
  const int row0 = by * 128, col0 = bx * 128;
  const int wr = w >> 1, wc = w & 1;
  f32x4 acc[4][4] = {};
  const int NK = K >> 5;

  for (int kt = 0; kt < NK; ++kt) {
    const int k0 = kt * 32;
    __syncthreads();
#pragma unroll
    for (int p = 0; p < 2; ++p) {
      const int cidx = p * 4 + w;
      const int r = cidx * 16 + (l >> 2);
      const int c8 = (l & 3) * 8;
      async16(A + (size_t)(row0 + r) * K + k0 + c8, (char*)As + cidx * 1024);
      async16(Bt + (size_t)(col0 + r) * K + k0 + c8, (char*)Bs + cidx * 1024);
    }
    asm volatile("s_waitcnt vmcnt(0)" ::: "memory");
    __syncthreads();

    bf16x8 af[4], bfr[4];
#pragma unroll
    for (int m = 0; m < 4; ++m)
      af[m] = *(const bf16x8*)((const char*)As + (wr * 64 + m * 16 + (l & 15)) * 64 + (l >> 4) * 16);
#pragma unroll
    for (int n = 0; n < 4; ++n)
      bfr[n] = *(const bf16x8*)((const char*)Bs + (wc * 64 + n * 16 + (l & 15)) * 64 + (l >> 4) * 16);
#pragma unroll
    for (int m = 0; m < 4; ++m)
#pragma unroll
      for (int n = 0; n < 4; ++n)
        acc[m][n] = __builtin_amdgcn_mfma_f32_16x16x32_bf16(af[m], bfr[n], acc[m][n], 0, 0, 0);
  }

  if (VSPLIT && col0 >= VOFF) {
    // transposed V epilogue: vtg[(b*NKVH+kvh)*HD + d][s], 4 consecutive s per write
#pragma unroll
    for (int m = 0; m < 4; ++m) {
      const int row = row0 + wr * 64 + m * 16 + (l >> 4) * 4;
      const int bb_ = row >> 11, s = row & 2047;
#pragma unroll
      for (int n = 0; n < 4; ++n) {
        const int col = col0 + wc * 64 + n * 16 + (l & 15);
        const int kvh = (col - VOFF) >> 7, d = (col - VOFF) & 127;
        const float bv = HAS_BIAS ? bias[col] : 0.f;
        u32 x = (u32)f2bf(acc[m][n][0] + bv) | ((u32)f2bf(acc[m][n][1] + bv) << 16);
        u32 y = (u32)f2bf(acc[m][n][2] + bv) | ((u32)f2bf(acc[m][n][3] + bv) << 16);
        uint2 r2; r2.x = x; r2.y = y;
        *(uint2*)(vtg + ((size_t)((bb_ * NKVH + kvh) * HD + d)) * NS + s) = r2;
      }
    }
    return;
  }

#pragma unroll
  for (int m = 0; m < 4; ++m) {
    const int row = row0 + wr * 64 + m * 16 + (l >> 4) * 4;
#pragma unroll
    for (int n = 0; n < 4; ++n) {
      const int col = col0 + wc * 64 + n * 16 + (l & 15);
      float bb = HAS_BIAS ? bias[col] : 0.f;
#pragma unroll
      for (int j = 0; j < 4; ++j) {
        float v = acc[m][n][j] + bb;
        if (OUT_BF16) outb[(size_t)(row + j) * N + col] = f2bf(v);
        else          outf[(size_t)(row + j) * N + col] = v;
      }
    }
  }
}

// ---------------- causal GQA flash attention -----------------------------------
// 4 waves, QBLK=64, KVBLK=64; K and V^T staged via global_load_lds (pre-swizzled
// source -> XOR-swizzled ds_read_b128), double-buffered; online softmax.
__global__ __launch_bounds__(256) void attn_kernel(const u16* __restrict__ qkv,
                                                   const u16* __restrict__ vtg,
                                                   u16* __restrict__ Oh) {
  __shared__ __align__(16) u16 Ks[2][64 * 128];   // [key][d] swizzled, 16KB each
  __shared__ __align__(16) u16 Vt[2][128 * 64];   // [d][key] swizzled, 16KB each
  __shared__ __align__(16) u16 Pl[4 * 16 * 64];   // per-wave P, swizzled, 8KB
  const int tid = threadIdx.x, l = tid & 63, w = tid >> 6;
  const int bidx = blockIdx.x;
  const int qt = 31 - (bidx & 31);               // heavy tiles first
  const int bh = bidx >> 5;
  const int h = bh % NHEAD, b = bh / NHEAD;
  const int kvh = h / 7;
  const int q0 = qt * 64;

  // Q fragments (A-frag: row = l&15, k = ks*32 + (l>>4)*8)
  const int qrow = q0 + w * 16 + (l & 15);
  const size_t qbase = (size_t)(b * NS + qrow) * QKVW + h * HD;
  bf16x8 qf[4];
#pragma unroll
  for (int ks = 0; ks < 4; ++ks)
    qf[ks] = *(const bf16x8*)(qkv + qbase + ks * 32 + (l >> 4) * 8);

  const u16* kb0 = qkv + (size_t)(b * NS) * QKVW + KOFF + kvh * HD;
  const u16* vb0 = vtg + (size_t)((b * NKVH + kvh) * HD) * NS;

  f32x4 oacc[8] = {};
  float mrun[4], lrun[4];
#pragma unroll
  for (int j = 0; j < 4; ++j) { mrun[j] = -1e30f; lrun[j] = 0.f; }

  const int nkv = qt + 1;

  // ---- staging (global_load_lds, linear dest + inverse-swizzled source) ----
  auto stage = [&](u16* kdst, u16* vdst, int kv0) {
#pragma unroll
    for (int i = 0; i < 4; ++i) {
      const int li = (w * 4 + i) * 64 + l;
      const int r = li >> 4, c = li & 15;          // K: row=key, 16 chunks/row
      async16(kb0 + (size_t)(kv0 + r) * QKVW + ((c ^ (r & 7)) << 3),
              (char*)kdst + (w * 4 + i) * 1024);
    }
#pragma unroll
    for (int i = 0; i < 4; ++i) {
      const int li = (w * 4 + i) * 64 + l;
      const int d = li >> 3, c = li & 7;           // V^T: row=d, 8 chunks/row
      async16(vb0 + (size_t)d * NS + kv0 + ((c ^ (d & 7)) << 3),
              (char*)vdst + (w * 4 + i) * 1024);
    }
  };

  stage(Ks[0], Vt[0], 0);
  asm volatile("s_waitcnt vmcnt(0)" ::: "memory");
  __syncthreads();
  int cur = 0;

  for (int kvt = 0; kvt < nkv; ++kvt) {
    const int kv0 = kvt * 64;
    if (kvt + 1 < nkv) stage(Ks[cur ^ 1], Vt[cur ^ 1], kv0 + 64);

    // ---- QK^T: 16 MFMA ----
    f32x4 sacc[4] = {};
    const char* ksB = (const char*)Ks[cur];
#pragma unroll
    for (int n = 0; n < 4; ++n) {
      const int key = n * 16 + (l & 15);
      const int sw = (key & 7) << 4;
#pragma unroll
      for (int ks = 0; ks < 4; ++ks) {
        bf16x8 kf = *(const bf16x8*)(ksB + key * 256 + ((ks * 64 + (l >> 4) * 16) ^ sw));
        sacc[n] = __builtin_amdgcn_mfma_f32_16x16x32_bf16(qf[ks], kf, sacc[n], 0, 0, 0);
      }
    }
    // ---- causal mask (diagonal tile only) ----
    if (kvt == qt) {
#pragma unroll
      for (int n = 0; n < 4; ++n) {
        const int key_g = kv0 + n * 16 + (l & 15);
#pragma unroll
        for (int j = 0; j < 4; ++j) {
          const int q_g = q0 + w * 16 + (l >> 4) * 4 + j;
          if (key_g > q_g) sacc[n][j] = -1e30f;
        }
      }
    }
    // ---- online softmax (16-lane-group shuffle reduce) ----
#pragma unroll
    for (int j = 0; j < 4; ++j) {
      float mx = fmaxf(fmaxf(sacc[0][j], sacc[1][j]), fmaxf(sacc[2][j], sacc[3][j]));
#pragma unroll
      for (int mk = 1; mk < 16; mk <<= 1) mx = fmaxf(mx, __shfl_xor(mx, mk, 64));
      const float mnew = fmaxf(mrun[j], mx);
      const float scale = __expf(mrun[j] - mnew);
      mrun[j] = mnew;
      float sum = 0.f;
#pragma unroll
      for (int n = 0; n < 4; ++n) {
        float p = __expf(sacc[n][j] - mnew);
        sacc[n][j] = p;
        sum += p;
      }
#pragma unroll
      for (int mk = 1; mk < 16; mk <<= 1) sum += __shfl_xor(sum, mk, 64);
      lrun[j] = lrun[j] * scale + sum;
#pragma unroll
      for (int dt = 0; dt < 8; ++dt) oacc[dt][j] *= scale;
    }
    // ---- P -> per-wave LDS (swizzled), then PV: 16 MFMA ----
#pragma unroll
    for (int n = 0; n < 4; ++n)
#pragma unroll
      for (int j = 0; j < 4; ++j) {
        const int prow = (l >> 4) * 4 + j;
        const int pcol = n * 16 + (l & 15);
        *(u16*)((char*)Pl + w * 2048 + prow * 128 + ((pcol * 2) ^ ((prow & 7) << 4))) =
            f2bf(sacc[n][j]);
      }
    asm volatile("s_waitcnt lgkmcnt(0)" ::: "memory");
    const char* vtB = (const char*)Vt[cur];
#pragma unroll
    for (int ks2 = 0; ks2 < 2; ++ks2) {
      bf16x8 pf = *(const bf16x8*)((const char*)Pl + w * 2048 + (l & 15) * 128 +
                                   ((ks2 * 64 + (l >> 4) * 16) ^ ((l & 7) << 4)));
#pragma unroll
      for (int dt = 0; dt < 8; ++dt) {
        const int d = dt * 16 + (l & 15);
        bf16x8 vf = *(const bf16x8*)(vtB + d * 128 +
                                     ((ks2 * 64 + (l >> 4) * 16) ^ ((d & 7) << 4)));
        oacc[dt] = __builtin_amdgcn_mfma_f32_16x16x32_bf16(pf, vf, oacc[dt], 0, 0, 0);
      }
    }

    asm volatile("s_waitcnt vmcnt(0)" ::: "memory");
    __syncthreads();
    cur ^= 1;
  }

  // ---- epilogue: O /= l, write bf16 [token][h*128+d] ----
#pragma unroll
  for (int j = 0; j < 4; ++j) {
    const float inv = 1.f / lrun[j];
    const int row = q0 + w * 16 + (l >> 4) * 4 + j;
    const size_t obase = (size_t)(b * NS + row) * QSZ + h * HD;
#pragma unroll
    for (int dt = 0; dt < 8; ++dt)
      Oh[obase + dt * 16 + (l & 15)] = f2bf(oacc[dt][j] * inv);
  }
}

// -------------------------------------------------------------------------------
extern "C" void kernel_launch(void* const* d_in, const int* in_sizes, int n_in,
                              void* d_out, int out_size, void* d_ws, size_t ws_size,
                              hipStream_t stream) {
  const int* positions = (const int*)d_in[0];
  const float* hidden = (const float*)d_in[1];
  const float* w_qkv = (const float*)d_in[2];
  const float* b_qkv = (const float*)d_in[3];
  const float* w_o = (const float*)d_in[4];
  float* out = (float*)d_out;

  char* ws = (char*)d_ws;
  const size_t XB_OFF = 0;                           // 29,360,128 B (later reused by WoT)
  const size_t WQT_OFF = 29360128;                   // 33,030,144 B (later reused by Oh)
  const size_t QKV_OFF = WQT_OFF + 33030144;         // 37,748,736 B
  const size_t CS_OFF = QKV_OFF + 37748736;          // 1,048,576 B
  const size_t SN_OFF = CS_OFF + 1048576;            // 1,048,576 B
  const size_t WS_NEED = SN_OFF + 1048576;           // ~102.2 MB (known-safe)
  if (ws_size < WS_NEED) return;

  u16* Xb = (u16*)(ws + XB_OFF);
  u16* WoT = (u16*)(ws + XB_OFF);    // alias: after GEMM1 consumed Xb
  u16* WqT = (u16*)(ws + WQT_OFF);
  u16* Oh = (u16*)(ws + WQT_OFF);    // alias: after GEMM1 consumed WqT
  u16* qkvb = (u16*)(ws + QKV_OFF);
  float* cs = (float*)(ws + CS_OFF);
  float* sn = (float*)(ws + SN_OFF);
  // V^T scratch lives in d_out (4MB of 56MB); GEMM2 fully overwrites d_out later.
  u16* vtg = (u16*)d_out;

  cast_f32_bf16<<<14336, 256, 0, stream>>>(hidden, Xb);
  transpose_cast<<<dim3(QKVW / 32, HIDDEN_DIM / 32), 256, 0, stream>>>(w_qkv, WqT, HIDDEN_DIM, QKVW);
  rope_table<<<(NTOK * 64) / 256, 256, 0, stream>>>(positions, cs, sn);

  // QKV projection (+bias); V columns written transposed to vtg
  gemm128<true, true, true><<<(QKVW / 128) * (NTOK / 128), 256, 0, stream>>>(
      Xb, WqT, b_qkv, qkvb, nullptr, vtg, NTOK, QKVW, HIDDEN_DIM);

  rope_kernel<<<(NTOK * 32) / 4, 256, 0, stream>>>(qkvb, cs, sn);

  transpose_cast<<<dim3(HIDDEN_DIM / 32, QSZ / 32), 256, 0, stream>>>(w_o, WoT, QSZ, HIDDEN_DIM);

  attn_kernel<<<NB * NHEAD * (NS / 64), 256, 0, stream>>>(qkvb, vtg, Oh);

  gemm128<false, false, false><<<(HIDDEN_DIM / 128) * (NTOK / 128), 256, 0, stream>>>(
      Oh, WoT, nullptr, nullptr, out, nullptr, NTOK, HIDDEN_DIM, QSZ);
}

// Round 3
// 728.990 us; speedup vs baseline: 1.4795x; 1.0878x over previous
//
#include <hip/hip_runtime.h>

typedef unsigned short u16;
typedef unsigned int u32;
typedef __bf16 bf16x8 __attribute__((ext_vector_type(8)));
typedef float f32x4 __attribute__((ext_vector_type(4)));

#define NHEAD 28
#define NKVH 4
#define HD 128
#define NB 2
#define NS 2048
#define NTOK 4096
#define HIDDEN_DIM 3584
#define QKVW 4608
#define QSZ 3584
#define KOFF 3584
#define VOFF 4096
// QSCALE * log2(e): softmax runs in exp2 domain (v_exp_f32 is 2^x)
#define QSCALE_L2E 0.12751744f

__device__ __forceinline__ float bf2f(u16 u) {
  u32 x = ((u32)u) << 16; float f; __builtin_memcpy(&f, &x, 4); return f;
}
__device__ __forceinline__ u16 f2bf(float f) {
  u32 x; __builtin_memcpy(&x, &f, 4);
  x += 0x7FFFu + ((x >> 16) & 1u);
  return (u16)(x >> 16);
}
__device__ __forceinline__ u32 pack2bf(float a, float b) {
  return (u32)f2bf(a) | ((u32)f2bf(b) << 16);
}
__device__ __forceinline__ void async16(const void* g, void* lds) {
  __builtin_amdgcn_global_load_lds((const __attribute__((address_space(1))) void*)g,
                                   (__attribute__((address_space(3))) void*)lds,
                                   16, 0, 0);
}

// ---------------- elementwise f32 -> bf16 cast (4 elems/thread) ----------------
__global__ void cast_f32_bf16(const float* __restrict__ in, u16* __restrict__ out) {
  int i = (blockIdx.x * 256 + threadIdx.x) * 4;
  float4 v = *(const float4*)(in + i);
  u32 p0 = (u32)f2bf(v.x) | ((u32)f2bf(v.y) << 16);
  u32 p1 = (u32)f2bf(v.z) | ((u32)f2bf(v.w) << 16);
  uint2 r; r.x = p0; r.y = p1;
  *(uint2*)(out + i) = r;
}

// ------------- tiled transpose + cast: in f32 [R][C] -> out bf16 [C][R] --------
__global__ void transpose_cast(const float* __restrict__ in, u16* __restrict__ out,
                               int R, int C) {
  __shared__ float tile[32][33];
  int tx = threadIdx.x & 31, ty = threadIdx.x >> 5;   // 32 x 8
  int c0 = blockIdx.x * 32, r0 = blockIdx.y * 32;
#pragma unroll
  for (int i = 0; i < 32; i += 8)
    tile[ty + i][tx] = in[(size_t)(r0 + ty + i) * C + c0 + tx];
  __syncthreads();
#pragma unroll
  for (int i = 0; i < 32; i += 8)
    out[(size_t)(c0 + ty + i) * R + r0 + tx] = f2bf(tile[tx][ty + i]);
}

// ---------------- rope cos/sin table: [NTOK][64] each --------------------------
__global__ void rope_table(const int* __restrict__ positions,
                           float* __restrict__ cs, float* __restrict__ sn) {
  int idx = blockIdx.x * 256 + threadIdx.x;   // NTOK*64
  int t = idx >> 6, i = idx & 63;
  float p = (float)positions[t];
  float inv = expf(-(float)i * (13.815510557964274f / 64.f));
  float a = p * inv;
  cs[idx] = cosf(a);
  sn[idx] = sinf(a);
}

// --------- in-place RoPE on qkv (q scaled by D^-0.5 * log2e for exp2-softmax) --
__global__ void rope_kernel(u16* __restrict__ qkv, const float* __restrict__ cs,
                            const float* __restrict__ sn) {
  int w = threadIdx.x >> 6, l = threadIdx.x & 63;
  int rid = blockIdx.x * 4 + w;          // NTOK * 32 head-rows
  int t = rid >> 5, hh = rid & 31;
  size_t base = (size_t)t * QKVW + (hh < NHEAD ? hh * HD : KOFF + (hh - NHEAD) * HD);
  float x1 = bf2f(qkv[base + l]), x2 = bf2f(qkv[base + l + 64]);
  float c = cs[t * 64 + l], s = sn[t * 64 + l];
  float y1 = x1 * c - x2 * s;
  float y2 = x2 * c + x1 * s;
  if (hh < NHEAD) { y1 *= QSCALE_L2E; y2 *= QSCALE_L2E; }
  qkv[base + l] = f2bf(y1);
  qkv[base + l + 64] = f2bf(y2);
}

// ---------------- 128x128 MFMA GEMM, A [M][K] bf16, Bt [N][K] bf16 -------------
// m97 structure. VSPLIT: tiles in the V column range write TRANSPOSED to vtg
// (layout [(b*NKVH+kvh)*HD+d][NS]) instead of the row-major output.
template <bool OUT_BF16, bool HAS_BIAS, bool VSPLIT>
__global__ __launch_bounds__(256) void gemm128(
    const u16* __restrict__ A, const u16* __restrict__ Bt,
    const float* __restrict__ bias, u16* __restrict__ outb,
    float* __restrict__ outf, u16* __restrict__ vtg, int M, int N, int K) {
  __shared__ __align__(16) u16 As[128 * 32];
  __shared__ __align__(16) u16 Bs[128 * 32];
  const int tid = threadIdx.x;
  const int l = tid & 63, w = tid >> 6;
  const int nbx = N >> 7;
  const int bx = blockIdx.x % nbx, by = blockIdx.x / nbx;
  const int row0 = by * 128, col0 = bx * 128;
  const int wr = w >> 1, wc = w & 1;
  f32x4 acc[4][4] = {};
  const int NK = K >> 5;

  for (int kt = 0; kt < NK; ++kt) {
    const int k0 = kt * 32;
    __syncthreads();
#pragma unroll
    for (int p = 0; p < 2; ++p) {
      const int cidx = p * 4 + w;
      const int r = cidx * 16 + (l >> 2);
      const int c8 = (l & 3) * 8;
      async16(A + (size_t)(row0 + r) * K + k0 + c8, (char*)As + cidx * 1024);
      async16(Bt + (size_t)(col0 + r) * K + k0 + c8, (char*)Bs + cidx * 1024);
    }
    asm volatile("s_waitcnt vmcnt(0)" ::: "memory");
    __syncthreads();

    bf16x8 af[4], bfr[4];
#pragma unroll
    for (int m = 0; m < 4; ++m)
      af[m] = *(const bf16x8*)((const char*)As + (wr * 64 + m * 16 + (l & 15)) * 64 + (l >> 4) * 16);
#pragma unroll
    for (int n = 0; n < 4; ++n)
      bfr[n] = *(const bf16x8*)((const char*)Bs + (wc * 64 + n * 16 + (l & 15)) * 64 + (l >> 4) * 16);
#pragma unroll
    for (int m = 0; m < 4; ++m)
#pragma unroll
      for (int n = 0; n < 4; ++n)
        acc[m][n] = __builtin_amdgcn_mfma_f32_16x16x32_bf16(af[m], bfr[n], acc[m][n], 0, 0, 0);
  }

  if (VSPLIT && col0 >= VOFF) {
    // transposed V epilogue: vtg[(b*NKVH+kvh)*HD + d][s], 4 consecutive s per write
#pragma unroll
    for (int m = 0; m < 4; ++m) {
      const int row = row0 + wr * 64 + m * 16 + (l >> 4) * 4;
      const int bb_ = row >> 11, s = row & 2047;
#pragma unroll
      for (int n = 0; n < 4; ++n) {
        const int col = col0 + wc * 64 + n * 16 + (l & 15);
        const int kvh = (col - VOFF) >> 7, d = (col - VOFF) & 127;
        const float bv = HAS_BIAS ? bias[col] : 0.f;
        u32 x = pack2bf(acc[m][n][0] + bv, acc[m][n][1] + bv);
        u32 y = pack2bf(acc[m][n][2] + bv, acc[m][n][3] + bv);
        uint2 r2; r2.x = x; r2.y = y;
        *(uint2*)(vtg + ((size_t)((bb_ * NKVH + kvh) * HD + d)) * NS + s) = r2;
      }
    }
    return;
  }

#pragma unroll
  for (int m = 0; m < 4; ++m) {
    const int row = row0 + wr * 64 + m * 16 + (l >> 4) * 4;
#pragma unroll
    for (int n = 0; n < 4; ++n) {
      const int col = col0 + wc * 64 + n * 16 + (l & 15);
      float bb = HAS_BIAS ? bias[col] : 0.f;
#pragma unroll
      for (int j = 0; j < 4; ++j) {
        float v = acc[m][n][j] + bb;
        if (OUT_BF16) outb[(size_t)(row + j) * N + col] = f2bf(v);
        else          outf[(size_t)(row + j) * N + col] = v;
      }
    }
  }
}

// ---------------- causal GQA flash attention (swapped-operand form) ------------
// 4 waves, QBLK=64, KVBLK=64. QK^T computed as mfma(K,Q) -> S^T (col = q-row),
// so softmax is per-lane over 16 values + 2 shuffles; PV as mfma(V^T,P) -> O^T.
// P reaches the PV B-fragment via in-register shuffles (no LDS round-trip).
// K double-buffered + V single-buffered via global_load_lds, counted vmcnt.
__global__ __launch_bounds__(256) void attn_kernel(const u16* __restrict__ qkv,
                                                   const u16* __restrict__ vtg,
                                                   u16* __restrict__ Oh) {
  __shared__ __align__(16) u16 Ks[2][64 * 128];   // [key][d] swizzled, 16KB each
  __shared__ __align__(16) u16 Vt[128 * 64];      // [d][key] swizzled, 16KB
  const int tid = threadIdx.x, l = tid & 63, w = tid >> 6;
  const int g = l >> 4, r = l & 15;
  const int bidx = blockIdx.x;
  const int qt = 31 - (bidx & 31);               // heavy tiles first
  const int bh = bidx >> 5;
  const int h = bh % NHEAD, b = bh / NHEAD;
  const int kvh = h / 7;
  const int q0 = qt * 64;

  // Q fragment (B-frag role: col = r = q-row, k = ks*32 + g*8 + i)
  const int qrow = q0 + w * 16 + r;
  const size_t qbase = (size_t)(b * NS + qrow) * QKVW + h * HD;
  bf16x8 qf[4];
#pragma unroll
  for (int ks = 0; ks < 4; ++ks)
    qf[ks] = *(const bf16x8*)(qkv + qbase + ks * 32 + g * 8);

  const u16* kb0 = qkv + (size_t)(b * NS) * QKVW + KOFF + kvh * HD;
  const u16* vb0 = vtg + (size_t)((b * NKVH + kvh) * HD) * NS;

  f32x4 oacc[8] = {};           // O^T: oacc[dt][j] = O[qrow=r][d=dt*16+4g+j]
  float mrun = -1e30f, lrun = 0.f;

  const int nkv = qt + 1;

  auto stageK = [&](u16* kdst, int kv0) {
#pragma unroll
    for (int i = 0; i < 4; ++i) {
      const int li = (w * 4 + i) * 64 + l;
      const int rr = li >> 4, c = li & 15;
      async16(kb0 + (size_t)(kv0 + rr) * QKVW + ((c ^ (rr & 7)) << 3),
              (char*)kdst + (w * 4 + i) * 1024);
    }
  };
  auto stageV = [&](int kv0) {
#pragma unroll
    for (int i = 0; i < 4; ++i) {
      const int li = (w * 4 + i) * 64 + l;
      const int d = li >> 3, c = li & 7;
      async16(vb0 + (size_t)d * NS + kv0 + ((c ^ (d & 7)) << 3),
              (char*)Vt + (w * 4 + i) * 1024);
    }
  };

  stageK(Ks[0], 0);
  int cur = 0;
  // shuffle sources for the P exchange (same r, groups 2(g&1) and 2(g&1)+1)
  const int srcA = r + ((l & 16) << 1);
  const int srcB = srcA + 16;
  const bool hi = (l & 32) != 0;                 // g>>1

  for (int kvt = 0; kvt < nkv; ++kvt) {
    const int kv0 = kvt * 64;
    asm volatile("s_waitcnt vmcnt(0) lgkmcnt(0)" ::: "memory");
    __builtin_amdgcn_s_barrier();               // K[cur] landed everywhere; Vt free
    __builtin_amdgcn_sched_barrier(0);

    stageV(kv0);                                // 4 async16 / thread
    const bool haveNext = (kvt + 1 < nkv);
    if (haveNext) stageK(Ks[cur ^ 1], kv0 + 64);

    // ---- QK^T swapped: sacc[n] = S^T[key=n*16+4g+j][qrow=r] ----
    f32x4 sacc[4] = {};
    const char* ksB = (const char*)Ks[cur];
#pragma unroll
    for (int n = 0; n < 4; ++n) {
      const int key = n * 16 + r;
      const int sw = (key & 7) << 4;
#pragma unroll
      for (int ks = 0; ks < 4; ++ks) {
        bf16x8 kf = *(const bf16x8*)(ksB + key * 256 + ((ks * 64 + g * 16) ^ sw));
        sacc[n] = __builtin_amdgcn_mfma_f32_16x16x32_bf16(kf, qf[ks], sacc[n], 0, 0, 0);
      }
    }
    // ---- causal mask (diagonal tile only) ----
    if (kvt == qt) {
#pragma unroll
      for (int n = 0; n < 4; ++n) {
        const int key_g = kv0 + n * 16 + g * 4;
#pragma unroll
        for (int j = 0; j < 4; ++j)
          if (key_g + j > qrow) sacc[n][j] = -1e30f;
      }
    }
    // ---- per-lane online softmax (exp2 domain) ----
    float mx = fmaxf(fmaxf(sacc[0][0], sacc[0][1]), fmaxf(sacc[0][2], sacc[0][3]));
#pragma unroll
    for (int n = 1; n < 4; ++n)
      mx = fmaxf(mx, fmaxf(fmaxf(sacc[n][0], sacc[n][1]), fmaxf(sacc[n][2], sacc[n][3])));
    mx = fmaxf(mx, __shfl_xor(mx, 16, 64));
    mx = fmaxf(mx, __shfl_xor(mx, 32, 64));
    const float mnew = fmaxf(mrun, mx);
    const float scale = exp2f(mrun - mnew);
    mrun = mnew;
    float sum = 0.f;
#pragma unroll
    for (int n = 0; n < 4; ++n)
#pragma unroll
      for (int j = 0; j < 4; ++j) {
        float p = exp2f(sacc[n][j] - mnew);
        sacc[n][j] = p;
        sum += p;
      }
    sum += __shfl_xor(sum, 16, 64);
    sum += __shfl_xor(sum, 32, 64);
    lrun = lrun * scale + sum;
#pragma unroll
    for (int dt = 0; dt < 8; ++dt) oacc[dt] *= scale;

    // ---- pack P to bf16 pairs, exchange to PV B-fragments in-register ----
    u32 pk[4][2];
#pragma unroll
    for (int n = 0; n < 4; ++n) {
      pk[n][0] = pack2bf(sacc[n][0], sacc[n][1]);
      pk[n][1] = pack2bf(sacc[n][2], sacc[n][3]);
    }
    union { u32 wrd[4]; bf16x8 v; } pf[2];
#pragma unroll
    for (int ks2 = 0; ks2 < 2; ++ks2) {
      const int n0 = 2 * ks2, n1 = 2 * ks2 + 1;
#pragma unroll
      for (int hh2 = 0; hh2 < 2; ++hh2) {
        u32 a0 = (u32)__shfl((int)pk[n0][hh2], srcA, 64);
        u32 a1 = (u32)__shfl((int)pk[n1][hh2], srcA, 64);
        pf[ks2].wrd[hh2] = hi ? a1 : a0;
        u32 b0 = (u32)__shfl((int)pk[n0][hh2], srcB, 64);
        u32 b1 = (u32)__shfl((int)pk[n1][hh2], srcB, 64);
        pf[ks2].wrd[2 + hh2] = hi ? b1 : b0;
      }
    }

    // ---- PV swapped: oacc[dt] += V^T[d-block dt] x P ----
    if (haveNext) asm volatile("s_waitcnt vmcnt(4)" ::: "memory");
    else          asm volatile("s_waitcnt vmcnt(0)" ::: "memory");
    __builtin_amdgcn_s_barrier();               // V[cur] landed everywhere
    __builtin_amdgcn_sched_barrier(0);
    const char* vtB = (const char*)Vt;
#pragma unroll
    for (int ks2 = 0; ks2 < 2; ++ks2) {
#pragma unroll
      for (int dt = 0; dt < 8; ++dt) {
        const int d = dt * 16 + r;
        bf16x8 vf = *(const bf16x8*)(vtB + d * 128 +
                                     ((ks2 * 64 + g * 16) ^ ((d & 7) << 4)));
        oacc[dt] = __builtin_amdgcn_mfma_f32_16x16x32_bf16(vf, pf[ks2].v, oacc[dt], 0, 0, 0);
      }
    }
    cur ^= 1;
  }

  // ---- epilogue: O^T -> Oh[token][h*128+d], packed 8B stores ----
  const float inv = 1.f / lrun;
  const size_t obase = (size_t)(b * NS + qrow) * QSZ + h * HD;
#pragma unroll
  for (int dt = 0; dt < 8; ++dt) {
    uint2 r2;
    r2.x = pack2bf(oacc[dt][0] * inv, oacc[dt][1] * inv);
    r2.y = pack2bf(oacc[dt][2] * inv, oacc[dt][3] * inv);
    *(uint2*)(Oh + obase + dt * 16 + 4 * g) = r2;
  }
}

// -------------------------------------------------------------------------------
extern "C" void kernel_launch(void* const* d_in, const int* in_sizes, int n_in,
                              void* d_out, int out_size, void* d_ws, size_t ws_size,
                              hipStream_t stream) {
  const int* positions = (const int*)d_in[0];
  const float* hidden = (const float*)d_in[1];
  const float* w_qkv = (const float*)d_in[2];
  const float* b_qkv = (const float*)d_in[3];
  const float* w_o = (const float*)d_in[4];
  float* out = (float*)d_out;

  char* ws = (char*)d_ws;
  const size_t XB_OFF = 0;                           // 29,360,128 B (later reused by WoT)
  const size_t WQT_OFF = 29360128;                   // 33,030,144 B (later reused by Oh)
  const size_t QKV_OFF = WQT_OFF + 33030144;         // 37,748,736 B
  const size_t CS_OFF = QKV_OFF + 37748736;          // 1,048,576 B
  const size_t SN_OFF = CS_OFF + 1048576;            // 1,048,576 B
  const size_t WS_NEED = SN_OFF + 1048576;           // ~102.2 MB (known-safe)
  if (ws_size < WS_NEED) return;

  u16* Xb = (u16*)(ws + XB_OFF);
  u16* WoT = (u16*)(ws + XB_OFF);    // alias: after GEMM1 consumed Xb
  u16* WqT = (u16*)(ws + WQT_OFF);
  u16* Oh = (u16*)(ws + WQT_OFF);    // alias: after GEMM1 consumed WqT
  u16* qkvb = (u16*)(ws + QKV_OFF);
  float* cs = (float*)(ws + CS_OFF);
  float* sn = (float*)(ws + SN_OFF);
  // V^T scratch lives in d_out (4MB of 56MB); GEMM2 fully overwrites d_out later.
  u16* vtg = (u16*)d_out;

  cast_f32_bf16<<<14336, 256, 0, stream>>>(hidden, Xb);
  transpose_cast<<<dim3(QKVW / 32, HIDDEN_DIM / 32), 256, 0, stream>>>(w_qkv, WqT, HIDDEN_DIM, QKVW);
  rope_table<<<(NTOK * 64) / 256, 256, 0, stream>>>(positions, cs, sn);

  // QKV projection (+bias); V columns written transposed to vtg
  gemm128<true, true, true><<<(QKVW / 128) * (NTOK / 128), 256, 0, stream>>>(
      Xb, WqT, b_qkv, qkvb, nullptr, vtg, NTOK, QKVW, HIDDEN_DIM);

  rope_kernel<<<(NTOK * 32) / 4, 256, 0, stream>>>(qkvb, cs, sn);

  transpose_cast<<<dim3(HIDDEN_DIM / 32, QSZ / 32), 256, 0, stream>>>(w_o, WoT, QSZ, HIDDEN_DIM);

  attn_kernel<<<NB * NHEAD * (NS / 64), 256, 0, stream>>>(qkvb, vtg, Oh);

  gemm128<false, false, false><<<(HIDDEN_DIM / 128) * (NTOK / 128), 256, 0, stream>>>(
      Oh, WoT, nullptr, nullptr, out, nullptr, NTOK, HIDDEN_DIM, QSZ);
}

// Round 4
// 701.970 us; speedup vs baseline: 1.5365x; 1.0385x over previous
//
#include <hip/hip_runtime.h>

typedef unsigned short u16;
typedef unsigned int u32;
typedef __bf16 bf16x8 __attribute__((ext_vector_type(8)));
typedef float f32x4 __attribute__((ext_vector_type(4)));

#define NHEAD 28
#define NKVH 4
#define HD 128
#define NB 2
#define NS 2048
#define NTOK 4096
#define HIDDEN_DIM 3584
#define QKVW 4608
#define QSZ 3584
#define KOFF 3584
#define VOFF 4096
// QSCALE * log2(e): softmax runs in exp2 domain (v_exp_f32 is 2^x)
#define QSCALE_L2E 0.12751744f

__device__ __forceinline__ float bf2f(u16 u) {
  u32 x = ((u32)u) << 16; float f; __builtin_memcpy(&f, &x, 4); return f;
}
__device__ __forceinline__ u16 f2bf(float f) {
  u32 x; __builtin_memcpy(&x, &f, 4);
  x += 0x7FFFu + ((x >> 16) & 1u);
  return (u16)(x >> 16);
}
__device__ __forceinline__ u32 pack2bf(float a, float b) {
  return (u32)f2bf(a) | ((u32)f2bf(b) << 16);
}
__device__ __forceinline__ void async16(const void* g, void* lds) {
  __builtin_amdgcn_global_load_lds((const __attribute__((address_space(1))) void*)g,
                                   (__attribute__((address_space(3))) void*)lds,
                                   16, 0, 0);
}

// ---------------- elementwise f32 -> bf16 cast (4 elems/thread) ----------------
__global__ void cast_f32_bf16(const float* __restrict__ in, u16* __restrict__ out) {
  int i = (blockIdx.x * 256 + threadIdx.x) * 4;
  float4 v = *(const float4*)(in + i);
  u32 p0 = (u32)f2bf(v.x) | ((u32)f2bf(v.y) << 16);
  u32 p1 = (u32)f2bf(v.z) | ((u32)f2bf(v.w) << 16);
  uint2 r; r.x = p0; r.y = p1;
  *(uint2*)(out + i) = r;
}

// ------------- tiled transpose + cast: in f32 [R][C] -> out bf16 [C][R] --------
__global__ void transpose_cast(const float* __restrict__ in, u16* __restrict__ out,
                               int R, int C) {
  __shared__ float tile[32][33];
  int tx = threadIdx.x & 31, ty = threadIdx.x >> 5;   // 32 x 8
  int c0 = blockIdx.x * 32, r0 = blockIdx.y * 32;
#pragma unroll
  for (int i = 0; i < 32; i += 8)
    tile[ty + i][tx] = in[(size_t)(r0 + ty + i) * C + c0 + tx];
  __syncthreads();
#pragma unroll
  for (int i = 0; i < 32; i += 8)
    out[(size_t)(c0 + ty + i) * R + r0 + tx] = f2bf(tile[tx][ty + i]);
}

// ---------------- rope cos/sin table: [NTOK][64] each --------------------------
__global__ void rope_table(const int* __restrict__ positions,
                           float* __restrict__ cs, float* __restrict__ sn) {
  int idx = blockIdx.x * 256 + threadIdx.x;   // NTOK*64
  int t = idx >> 6, i = idx & 63;
  float p = (float)positions[t];
  float inv = expf(-(float)i * (13.815510557964274f / 64.f));
  float a = p * inv;
  cs[idx] = cosf(a);
  sn[idx] = sinf(a);
}

// --------- in-place RoPE on qkv (q scaled by D^-0.5 * log2e for exp2-softmax) --
__global__ void rope_kernel(u16* __restrict__ qkv, const float* __restrict__ cs,
                            const float* __restrict__ sn) {
  int w = threadIdx.x >> 6, l = threadIdx.x & 63;
  int rid = blockIdx.x * 4 + w;          // NTOK * 32 head-rows
  int t = rid >> 5, hh = rid & 31;
  size_t base = (size_t)t * QKVW + (hh < NHEAD ? hh * HD : KOFF + (hh - NHEAD) * HD);
  float x1 = bf2f(qkv[base + l]), x2 = bf2f(qkv[base + l + 64]);
  float c = cs[t * 64 + l], s = sn[t * 64 + l];
  float y1 = x1 * c - x2 * s;
  float y2 = x2 * c + x1 * s;
  if (hh < NHEAD) { y1 *= QSCALE_L2E; y2 *= QSCALE_L2E; }
  qkv[base + l] = f2bf(y1);
  qkv[base + l + 64] = f2bf(y2);
}

// ---------------- 128x128 MFMA GEMM, A [M][K] bf16, Bt [N][K] bf16 -------------
// 2-phase double-buffered (T3 minimum recipe): stage next tile early, one
// vmcnt(0)+barrier per K-step. LDS frag reads bank-conflict-swizzled
// (slot ^= (row>>1)&3, applied on global source AND ds_read addr — rule 21).
// XCD-aware block swizzle (T1, grids divisible by 8).
// VSPLIT: tiles in the V column range write TRANSPOSED to vtg.
template <bool OUT_BF16, bool HAS_BIAS, bool VSPLIT>
__global__ __launch_bounds__(256) void gemm128(
    const u16* __restrict__ A, const u16* __restrict__ Bt,
    const float* __restrict__ bias, u16* __restrict__ outb,
    float* __restrict__ outf, u16* __restrict__ vtg, int M, int N, int K) {
  __shared__ __align__(16) u16 As[2][128 * 32];
  __shared__ __align__(16) u16 Bs[2][128 * 32];
  const int tid = threadIdx.x;
  const int l = tid & 63, w = tid >> 6;
  const int nbx = N >> 7;
  // T1: bijective XCD swizzle (gridDim.x % 8 == 0)
  const int cpx = (int)gridDim.x >> 3;
  const int bid = ((int)blockIdx.x & 7) * cpx + ((int)blockIdx.x >> 3);
  const int bx = bid % nbx, by = bid / nbx;
  const int row0 = by * 128, col0 = bx * 128;
  const int wr = w >> 1, wc = w & 1;
  f32x4 acc[4][4] = {};
  const int NK = K >> 5;

  // stage one 128x32 A-tile + B-tile into buffer d (4 async16/wave).
  // source slot pre-swizzled: s_src = (l&3) ^ ((rr>>1)&3), rr = cidx*16 + (l>>2)
  auto stage = [&](u16* dA, u16* dB, int k0) {
#pragma unroll
    for (int p = 0; p < 2; ++p) {
      const int cidx = p * 4 + w;
      const int rr = cidx * 16 + (l >> 2);
      const int ss = (l & 3) ^ ((l >> 3) & 3);
      async16(A + (size_t)(row0 + rr) * K + k0 + ss * 8, (char*)dA + cidx * 1024);
      async16(Bt + (size_t)(col0 + rr) * K + k0 + ss * 8, (char*)dB + cidx * 1024);
    }
  };

  stage(As[0], Bs[0], 0);
  asm volatile("s_waitcnt vmcnt(0)" ::: "memory");
  __syncthreads();
  int cur = 0;

  const int rsw = (l >> 1) & 3;          // (row>>1)&3 of the frag row (row bits 1-2 = l bits 1-2)
  for (int kt = 0; kt < NK; ++kt) {
    if (kt + 1 < NK) stage(As[cur ^ 1], Bs[cur ^ 1], (kt + 1) * 32);

    bf16x8 af[4], bfr[4];
    const char* aB = (const char*)As[cur];
    const char* bB = (const char*)Bs[cur];
#pragma unroll
    for (int m = 0; m < 4; ++m)
      af[m] = *(const bf16x8*)(aB + (wr * 64 + m * 16 + (l & 15)) * 64 +
                               (((l >> 4) ^ rsw) << 4));
#pragma unroll
    for (int n = 0; n < 4; ++n)
      bfr[n] = *(const bf16x8*)(bB + (wc * 64 + n * 16 + (l & 15)) * 64 +
                                (((l >> 4) ^ rsw) << 4));
#pragma unroll
    for (int m = 0; m < 4; ++m)
#pragma unroll
      for (int n = 0; n < 4; ++n)
        acc[m][n] = __builtin_amdgcn_mfma_f32_16x16x32_bf16(af[m], bfr[n], acc[m][n], 0, 0, 0);

    asm volatile("s_waitcnt vmcnt(0)" ::: "memory");
    __syncthreads();
    cur ^= 1;
  }

  if (VSPLIT && col0 >= VOFF) {
    // transposed V epilogue: vtg[(b*NKVH+kvh)*HD + d][s], 4 consecutive s per write
#pragma unroll
    for (int m = 0; m < 4; ++m) {
      const int row = row0 + wr * 64 + m * 16 + (l >> 4) * 4;
      const int bb_ = row >> 11, s = row & 2047;
#pragma unroll
      for (int n = 0; n < 4; ++n) {
        const int col = col0 + wc * 64 + n * 16 + (l & 15);
        const int kvh = (col - VOFF) >> 7, d = (col - VOFF) & 127;
        const float bv = HAS_BIAS ? bias[col] : 0.f;
        u32 x = pack2bf(acc[m][n][0] + bv, acc[m][n][1] + bv);
        u32 y = pack2bf(acc[m][n][2] + bv, acc[m][n][3] + bv);
        uint2 r2; r2.x = x; r2.y = y;
        *(uint2*)(vtg + ((size_t)((bb_ * NKVH + kvh) * HD + d)) * NS + s) = r2;
      }
    }
    return;
  }

#pragma unroll
  for (int m = 0; m < 4; ++m) {
    const int row = row0 + wr * 64 + m * 16 + (l >> 4) * 4;
#pragma unroll
    for (int n = 0; n < 4; ++n) {
      const int col = col0 + wc * 64 + n * 16 + (l & 15);
      float bb = HAS_BIAS ? bias[col] : 0.f;
#pragma unroll
      for (int j = 0; j < 4; ++j) {
        float v = acc[m][n][j] + bb;
        if (OUT_BF16) outb[(size_t)(row + j) * N + col] = f2bf(v);
        else          outf[(size_t)(row + j) * N + col] = v;
      }
    }
  }
}

// ---------------- causal GQA flash attention (swapped-operand form) ------------
// 4 waves, QBLK=64, KVBLK=64. QK^T computed as mfma(K,Q) -> S^T (col = q-row),
// so softmax is per-lane over 16 values + 2 shuffles; PV as mfma(V^T,P) -> O^T.
// P reaches the PV B-fragment via in-register shuffles (no LDS round-trip).
// K double-buffered + V single-buffered via global_load_lds, counted vmcnt.
__global__ __launch_bounds__(256) void attn_kernel(const u16* __restrict__ qkv,
                                                   const u16* __restrict__ vtg,
                                                   u16* __restrict__ Oh) {
  __shared__ __align__(16) u16 Ks[2][64 * 128];   // [key][d] swizzled, 16KB each
  __shared__ __align__(16) u16 Vt[128 * 64];      // [d][key] swizzled, 16KB
  const int tid = threadIdx.x, l = tid & 63, w = tid >> 6;
  const int g = l >> 4, r = l & 15;
  const int bidx = blockIdx.x;
  const int qt = 31 - (bidx & 31);               // heavy tiles first
  const int bh = bidx >> 5;
  const int h = bh % NHEAD, b = bh / NHEAD;
  const int kvh = h / 7;
  const int q0 = qt * 64;

  // Q fragment (B-frag role: col = r = q-row, k = ks*32 + g*8 + i)
  const int qrow = q0 + w * 16 + r;
  const size_t qbase = (size_t)(b * NS + qrow) * QKVW + h * HD;
  bf16x8 qf[4];
#pragma unroll
  for (int ks = 0; ks < 4; ++ks)
    qf[ks] = *(const bf16x8*)(qkv + qbase + ks * 32 + g * 8);

  const u16* kb0 = qkv + (size_t)(b * NS) * QKVW + KOFF + kvh * HD;
  const u16* vb0 = vtg + (size_t)((b * NKVH + kvh) * HD) * NS;

  f32x4 oacc[8] = {};           // O^T: oacc[dt][j] = O[qrow=r][d=dt*16+4g+j]
  float mrun = -1e30f, lrun = 0.f;

  const int nkv = qt + 1;

  auto stageK = [&](u16* kdst, int kv0) {
#pragma unroll
    for (int i = 0; i < 4; ++i) {
      const int li = (w * 4 + i) * 64 + l;
      const int rr = li >> 4, c = li & 15;
      async16(kb0 + (size_t)(kv0 + rr) * QKVW + ((c ^ (rr & 7)) << 3),
              (char*)kdst + (w * 4 + i) * 1024);
    }
  };
  auto stageV = [&](int kv0) {
#pragma unroll
    for (int i = 0; i < 4; ++i) {
      const int li = (w * 4 + i) * 64 + l;
      const int d = li >> 3, c = li & 7;
      async16(vb0 + (size_t)d * NS + kv0 + ((c ^ (d & 7)) << 3),
              (char*)Vt + (w * 4 + i) * 1024);
    }
  };

  stageK(Ks[0], 0);
  int cur = 0;
  // shuffle sources for the P exchange (same r, groups 2(g&1) and 2(g&1)+1)
  const int srcA = r + ((l & 16) << 1);
  const int srcB = srcA + 16;
  const bool hi = (l & 32) != 0;                 // g>>1

  for (int kvt = 0; kvt < nkv; ++kvt) {
    const int kv0 = kvt * 64;
    asm volatile("s_waitcnt vmcnt(0) lgkmcnt(0)" ::: "memory");
    __builtin_amdgcn_s_barrier();               // K[cur] landed everywhere; Vt free
    __builtin_amdgcn_sched_barrier(0);

    stageV(kv0);                                // 4 async16 / thread
    const bool haveNext = (kvt + 1 < nkv);
    if (haveNext) stageK(Ks[cur ^ 1], kv0 + 64);

    // ---- QK^T swapped: sacc[n] = S^T[key=n*16+4g+j][qrow=r] ----
    f32x4 sacc[4] = {};
    const char* ksB = (const char*)Ks[cur];
#pragma unroll
    for (int n = 0; n < 4; ++n) {
      const int key = n * 16 + r;
      const int sw = (key & 7) << 4;
#pragma unroll
      for (int ks = 0; ks < 4; ++ks) {
        bf16x8 kf = *(const bf16x8*)(ksB + key * 256 + ((ks * 64 + g * 16) ^ sw));
        sacc[n] = __builtin_amdgcn_mfma_f32_16x16x32_bf16(kf, qf[ks], sacc[n], 0, 0, 0);
      }
    }
    // ---- causal mask (diagonal tile only) ----
    if (kvt == qt) {
#pragma unroll
      for (int n = 0; n < 4; ++n) {
        const int key_g = kv0 + n * 16 + g * 4;
#pragma unroll
        for (int j = 0; j < 4; ++j)
          if (key_g + j > qrow) sacc[n][j] = -1e30f;
      }
    }
    // ---- per-lane online softmax (exp2 domain) ----
    float mx = fmaxf(fmaxf(sacc[0][0], sacc[0][1]), fmaxf(sacc[0][2], sacc[0][3]));
#pragma unroll
    for (int n = 1; n < 4; ++n)
      mx = fmaxf(mx, fmaxf(fmaxf(sacc[n][0], sacc[n][1]), fmaxf(sacc[n][2], sacc[n][3])));
    mx = fmaxf(mx, __shfl_xor(mx, 16, 64));
    mx = fmaxf(mx, __shfl_xor(mx, 32, 64));
    const float mnew = fmaxf(mrun, mx);
    const float scale = exp2f(mrun - mnew);
    mrun = mnew;
    float sum = 0.f;
#pragma unroll
    for (int n = 0; n < 4; ++n)
#pragma unroll
      for (int j = 0; j < 4; ++j) {
        float p = exp2f(sacc[n][j] - mnew);
        sacc[n][j] = p;
        sum += p;
      }
    sum += __shfl_xor(sum, 16, 64);
    sum += __shfl_xor(sum, 32, 64);
    lrun = lrun * scale + sum;
#pragma unroll
    for (int dt = 0; dt < 8; ++dt) oacc[dt] *= scale;

    // ---- pack P to bf16 pairs, exchange to PV B-fragments in-register ----
    u32 pk[4][2];
#pragma unroll
    for (int n = 0; n < 4; ++n) {
      pk[n][0] = pack2bf(sacc[n][0], sacc[n][1]);
      pk[n][1] = pack2bf(sacc[n][2], sacc[n][3]);
    }
    union { u32 wrd[4]; bf16x8 v; } pf[2];
#pragma unroll
    for (int ks2 = 0; ks2 < 2; ++ks2) {
      const int n0 = 2 * ks2, n1 = 2 * ks2 + 1;
#pragma unroll
      for (int hh2 = 0; hh2 < 2; ++hh2) {
        u32 a0 = (u32)__shfl((int)pk[n0][hh2], srcA, 64);
        u32 a1 = (u32)__shfl((int)pk[n1][hh2], srcA, 64);
        pf[ks2].wrd[hh2] = hi ? a1 : a0;
        u32 b0 = (u32)__shfl((int)pk[n0][hh2], srcB, 64);
        u32 b1 = (u32)__shfl((int)pk[n1][hh2], srcB, 64);
        pf[ks2].wrd[2 + hh2] = hi ? b1 : b0;
      }
    }

    // ---- PV swapped: oacc[dt] += V^T[d-block dt] x P ----
    if (haveNext) asm volatile("s_waitcnt vmcnt(4)" ::: "memory");
    else          asm volatile("s_waitcnt vmcnt(0)" ::: "memory");
    __builtin_amdgcn_s_barrier();               // V[cur] landed everywhere
    __builtin_amdgcn_sched_barrier(0);
    const char* vtB = (const char*)Vt;
#pragma unroll
    for (int ks2 = 0; ks2 < 2; ++ks2) {
#pragma unroll
      for (int dt = 0; dt < 8; ++dt) {
        const int d = dt * 16 + r;
        bf16x8 vf = *(const bf16x8*)(vtB + d * 128 +
                                     ((ks2 * 64 + g * 16) ^ ((d & 7) << 4)));
        oacc[dt] = __builtin_amdgcn_mfma_f32_16x16x32_bf16(vf, pf[ks2].v, oacc[dt], 0, 0, 0);
      }
    }
    cur ^= 1;
  }

  // ---- epilogue: O^T -> Oh[token][h*128+d], packed 8B stores ----
  const float inv = 1.f / lrun;
  const size_t obase = (size_t)(b * NS + qrow) * QSZ + h * HD;
#pragma unroll
  for (int dt = 0; dt < 8; ++dt) {
    uint2 r2;
    r2.x = pack2bf(oacc[dt][0] * inv, oacc[dt][1] * inv);
    r2.y = pack2bf(oacc[dt][2] * inv, oacc[dt][3] * inv);
    *(uint2*)(Oh + obase + dt * 16 + 4 * g) = r2;
  }
}

// -------------------------------------------------------------------------------
extern "C" void kernel_launch(void* const* d_in, const int* in_sizes, int n_in,
                              void* d_out, int out_size, void* d_ws, size_t ws_size,
                              hipStream_t stream) {
  const int* positions = (const int*)d_in[0];
  const float* hidden = (const float*)d_in[1];
  const float* w_qkv = (const float*)d_in[2];
  const float* b_qkv = (const float*)d_in[3];
  const float* w_o = (const float*)d_in[4];
  float* out = (float*)d_out;

  char* ws = (char*)d_ws;
  const size_t XB_OFF = 0;                           // 29,360,128 B (later reused by WoT)
  const size_t WQT_OFF = 29360128;                   // 33,030,144 B (later reused by Oh)
  const size_t QKV_OFF = WQT_OFF + 33030144;         // 37,748,736 B
  const size_t CS_OFF = QKV_OFF + 37748736;          // 1,048,576 B
  const size_t SN_OFF = CS_OFF + 1048576;            // 1,048,576 B
  const size_t WS_NEED = SN_OFF + 1048576;           // ~102.2 MB (known-safe)
  if (ws_size < WS_NEED) return;

  u16* Xb = (u16*)(ws + XB_OFF);
  u16* WoT = (u16*)(ws + XB_OFF);    // alias: after GEMM1 consumed Xb
  u16* WqT = (u16*)(ws + WQT_OFF);
  u16* Oh = (u16*)(ws + WQT_OFF);    // alias: after GEMM1 consumed WqT
  u16* qkvb = (u16*)(ws + QKV_OFF);
  float* cs = (float*)(ws + CS_OFF);
  float* sn = (float*)(ws + SN_OFF);
  // V^T scratch lives in d_out (4MB of 56MB); GEMM2 fully overwrites d_out later.
  u16* vtg = (u16*)d_out;

  cast_f32_bf16<<<14336, 256, 0, stream>>>(hidden, Xb);
  transpose_cast<<<dim3(QKVW / 32, HIDDEN_DIM / 32), 256, 0, stream>>>(w_qkv, WqT, HIDDEN_DIM, QKVW);
  rope_table<<<(NTOK * 64) / 256, 256, 0, stream>>>(positions, cs, sn);

  // QKV projection (+bias); V columns written transposed to vtg
  gemm128<true, true, true><<<(QKVW / 128) * (NTOK / 128), 256, 0, stream>>>(
      Xb, WqT, b_qkv, qkvb, nullptr, vtg, NTOK, QKVW, HIDDEN_DIM);

  rope_kernel<<<(NTOK * 32) / 4, 256, 0, stream>>>(qkvb, cs, sn);

  transpose_cast<<<dim3(HIDDEN_DIM / 32, QSZ / 32), 256, 0, stream>>>(w_o, WoT, QSZ, HIDDEN_DIM);

  attn_kernel<<<NB * NHEAD * (NS / 64), 256, 0, stream>>>(qkvb, vtg, Oh);

  gemm128<false, false, false><<<(HIDDEN_DIM / 128) * (NTOK / 128), 256, 0, stream>>>(
      Oh, WoT, nullptr, nullptr, out, nullptr, NTOK, HIDDEN_DIM, QSZ);
}

// Round 5
// 677.978 us; speedup vs baseline: 1.5908x; 1.0354x over previous
//
#include <hip/hip_runtime.h>

typedef unsigned short u16;
typedef unsigned int u32;
typedef __bf16 bf16x8 __attribute__((ext_vector_type(8)));
typedef float f32x4 __attribute__((ext_vector_type(4)));

#define NHEAD 28
#define NKVH 4
#define HD 128
#define NB 2
#define NS 2048
#define NTOK 4096
#define HIDDEN_DIM 3584
#define QKVW 4608
#define QSZ 3584
#define KOFF 3584
#define VOFF 4096
// QSCALE * log2(e): softmax runs in exp2 domain (v_exp_f32 is 2^x)
#define QSCALE_L2E 0.12751744f

__device__ __forceinline__ float bf2f(u16 u) {
  u32 x = ((u32)u) << 16; float f; __builtin_memcpy(&f, &x, 4); return f;
}
__device__ __forceinline__ u16 f2bf(float f) {
  u32 x; __builtin_memcpy(&x, &f, 4);
  x += 0x7FFFu + ((x >> 16) & 1u);
  return (u16)(x >> 16);
}
__device__ __forceinline__ u32 pack2bf(float a, float b) {
  return (u32)f2bf(a) | ((u32)f2bf(b) << 16);
}
__device__ __forceinline__ void async16(const void* g, void* lds) {
  __builtin_amdgcn_global_load_lds((const __attribute__((address_space(1))) void*)g,
                                   (__attribute__((address_space(3))) void*)lds,
                                   16, 0, 0);
}

// ---------------- elementwise f32 -> bf16 cast (4 elems/thread) ----------------
__global__ void cast_f32_bf16(const float* __restrict__ in, u16* __restrict__ out) {
  int i = (blockIdx.x * 256 + threadIdx.x) * 4;
  float4 v = *(const float4*)(in + i);
  u32 p0 = (u32)f2bf(v.x) | ((u32)f2bf(v.y) << 16);
  u32 p1 = (u32)f2bf(v.z) | ((u32)f2bf(v.w) << 16);
  uint2 r; r.x = p0; r.y = p1;
  *(uint2*)(out + i) = r;
}

// ------------- tiled transpose + cast: in f32 [R][C] -> out bf16 [C][R] --------
__global__ void transpose_cast(const float* __restrict__ in, u16* __restrict__ out,
                               int R, int C) {
  __shared__ float tile[32][33];
  int tx = threadIdx.x & 31, ty = threadIdx.x >> 5;   // 32 x 8
  int c0 = blockIdx.x * 32, r0 = blockIdx.y * 32;
#pragma unroll
  for (int i = 0; i < 32; i += 8)
    tile[ty + i][tx] = in[(size_t)(r0 + ty + i) * C + c0 + tx];
  __syncthreads();
#pragma unroll
  for (int i = 0; i < 32; i += 8)
    out[(size_t)(c0 + ty + i) * R + r0 + tx] = f2bf(tile[tx][ty + i]);
}

// ---------------- rope cos/sin table: [NTOK][64] each --------------------------
__global__ void rope_table(const int* __restrict__ positions,
                           float* __restrict__ cs, float* __restrict__ sn) {
  int idx = blockIdx.x * 256 + threadIdx.x;   // NTOK*64
  int t = idx >> 6, i = idx & 63;
  float p = (float)positions[t];
  float inv = expf(-(float)i * (13.815510557964274f / 64.f));
  float a = p * inv;
  cs[idx] = cosf(a);
  sn[idx] = sinf(a);
}

// --------- in-place RoPE on qkv (q scaled by D^-0.5 * log2e for exp2-softmax) --
__global__ void rope_kernel(u16* __restrict__ qkv, const float* __restrict__ cs,
                            const float* __restrict__ sn) {
  int w = threadIdx.x >> 6, l = threadIdx.x & 63;
  int rid = blockIdx.x * 4 + w;          // NTOK * 32 head-rows
  int t = rid >> 5, hh = rid & 31;
  size_t base = (size_t)t * QKVW + (hh < NHEAD ? hh * HD : KOFF + (hh - NHEAD) * HD);
  float x1 = bf2f(qkv[base + l]), x2 = bf2f(qkv[base + l + 64]);
  float c = cs[t * 64 + l], s = sn[t * 64 + l];
  float y1 = x1 * c - x2 * s;
  float y2 = x2 * c + x1 * s;
  if (hh < NHEAD) { y1 *= QSCALE_L2E; y2 *= QSCALE_L2E; }
  qkv[base + l] = f2bf(y1);
  qkv[base + l + 64] = f2bf(y2);
}

// ---------------- 128x128 MFMA GEMM, A [M][K] bf16, Bt [N][K] bf16 -------------
// 2-phase double-buffered; LDS frag reads bank-conflict-swizzled (both sides);
// XCD-aware bijective block swizzle. VSPLIT: V-column tiles write transposed.
template <bool OUT_BF16, bool HAS_BIAS, bool VSPLIT>
__global__ __launch_bounds__(256) void gemm128(
    const u16* __restrict__ A, const u16* __restrict__ Bt,
    const float* __restrict__ bias, u16* __restrict__ outb,
    float* __restrict__ outf, u16* __restrict__ vtg, int M, int N, int K) {
  __shared__ __align__(16) u16 As[2][128 * 32];
  __shared__ __align__(16) u16 Bs[2][128 * 32];
  const int tid = threadIdx.x;
  const int l = tid & 63, w = tid >> 6;
  const int nbx = N >> 7;
  const int cpx = (int)gridDim.x >> 3;
  const int bid = ((int)blockIdx.x & 7) * cpx + ((int)blockIdx.x >> 3);
  const int bx = bid % nbx, by = bid / nbx;
  const int row0 = by * 128, col0 = bx * 128;
  const int wr = w >> 1, wc = w & 1;
  f32x4 acc[4][4] = {};
  const int NK = K >> 5;

  auto stage = [&](u16* dA, u16* dB, int k0) {
#pragma unroll
    for (int p = 0; p < 2; ++p) {
      const int cidx = p * 4 + w;
      const int rr = cidx * 16 + (l >> 2);
      const int ss = (l & 3) ^ ((l >> 3) & 3);
      async16(A + (size_t)(row0 + rr) * K + k0 + ss * 8, (char*)dA + cidx * 1024);
      async16(Bt + (size_t)(col0 + rr) * K + k0 + ss * 8, (char*)dB + cidx * 1024);
    }
  };

  stage(As[0], Bs[0], 0);
  asm volatile("s_waitcnt vmcnt(0)" ::: "memory");
  __syncthreads();
  int cur = 0;

  const int rsw = (l >> 1) & 3;
  for (int kt = 0; kt < NK; ++kt) {
    if (kt + 1 < NK) stage(As[cur ^ 1], Bs[cur ^ 1], (kt + 1) * 32);

    bf16x8 af[4], bfr[4];
    const char* aB = (const char*)As[cur];
    const char* bB = (const char*)Bs[cur];
#pragma unroll
    for (int m = 0; m < 4; ++m)
      af[m] = *(const bf16x8*)(aB + (wr * 64 + m * 16 + (l & 15)) * 64 +
                               (((l >> 4) ^ rsw) << 4));
#pragma unroll
    for (int n = 0; n < 4; ++n)
      bfr[n] = *(const bf16x8*)(bB + (wc * 64 + n * 16 + (l & 15)) * 64 +
                                (((l >> 4) ^ rsw) << 4));
#pragma unroll
    for (int m = 0; m < 4; ++m)
#pragma unroll
      for (int n = 0; n < 4; ++n)
        acc[m][n] = __builtin_amdgcn_mfma_f32_16x16x32_bf16(af[m], bfr[n], acc[m][n], 0, 0, 0);

    asm volatile("s_waitcnt vmcnt(0)" ::: "memory");
    __syncthreads();
    cur ^= 1;
  }

  if (VSPLIT && col0 >= VOFF) {
#pragma unroll
    for (int m = 0; m < 4; ++m) {
      const int row = row0 + wr * 64 + m * 16 + (l >> 4) * 4;
      const int bb_ = row >> 11, s = row & 2047;
#pragma unroll
      for (int n = 0; n < 4; ++n) {
        const int col = col0 + wc * 64 + n * 16 + (l & 15);
        const int kvh = (col - VOFF) >> 7, d = (col - VOFF) & 127;
        const float bv = HAS_BIAS ? bias[col] : 0.f;
        u32 x = pack2bf(acc[m][n][0] + bv, acc[m][n][1] + bv);
        u32 y = pack2bf(acc[m][n][2] + bv, acc[m][n][3] + bv);
        uint2 r2; r2.x = x; r2.y = y;
        *(uint2*)(vtg + ((size_t)((bb_ * NKVH + kvh) * HD + d)) * NS + s) = r2;
      }
    }
    return;
  }

#pragma unroll
  for (int m = 0; m < 4; ++m) {
    const int row = row0 + wr * 64 + m * 16 + (l >> 4) * 4;
#pragma unroll
    for (int n = 0; n < 4; ++n) {
      const int col = col0 + wc * 64 + n * 16 + (l & 15);
      float bb = HAS_BIAS ? bias[col] : 0.f;
#pragma unroll
      for (int j = 0; j < 4; ++j) {
        float v = acc[m][n][j] + bb;
        if (OUT_BF16) outb[(size_t)(row + j) * N + col] = f2bf(v);
        else          outf[(size_t)(row + j) * N + col] = v;
      }
    }
  }
}

// ---------------- causal GQA flash attention (swapped-operand form) ------------
// 8 waves, QBLK=128 (16 q-rows/wave), KVBLK=64. QK^T as mfma(K,Q) -> S^T
// (col = q-row): per-lane softmax + 2 shuffles. PV as mfma(V^T,P) -> O^T.
// P exchanged in-register. K dbuf + V single-buf via global_load_lds, counted
// vmcnt. T13 defer-rescale; fully-masked waves skip compute; T5 setprio.
__global__ __launch_bounds__(512) void attn_kernel(const u16* __restrict__ qkv,
                                                   const u16* __restrict__ vtg,
                                                   u16* __restrict__ Oh) {
  __shared__ __align__(16) u16 Ks[2][64 * 128];   // [key][d] swizzled, 16KB each
  __shared__ __align__(16) u16 Vt[128 * 64];      // [d][key] swizzled, 16KB
  const int tid = threadIdx.x, l = tid & 63, w = tid >> 6;   // w 0..7
  const int g = l >> 4, r = l & 15;
  const int bidx = blockIdx.x;
  const int qt = 15 - (bidx & 15);               // heavy q-tiles first
  const int bh = bidx >> 4;
  const int h = bh % NHEAD, b = bh / NHEAD;
  const int kvh = h / 7;
  const int q0 = qt * 128;

  // Q fragment (B-frag role: col = r = q-row, k = ks*32 + g*8 + i)
  const int qrow = q0 + w * 16 + r;
  const size_t qbase = (size_t)(b * NS + qrow) * QKVW + h * HD;
  bf16x8 qf[4];
#pragma unroll
  for (int ks = 0; ks < 4; ++ks)
    qf[ks] = *(const bf16x8*)(qkv + qbase + ks * 32 + g * 8);

  const u16* kb0 = qkv + (size_t)(b * NS) * QKVW + KOFF + kvh * HD;
  const u16* vb0 = vtg + (size_t)((b * NKVH + kvh) * HD) * NS;

  f32x4 oacc[8] = {};           // O^T: oacc[dt][j] = O[qrow=r][d=dt*16+4g+j]
  float mrun = -1e30f, lrun = 0.f;

  const int nkv = 2 * qt + 2;

  auto stageK = [&](u16* kdst, int kv0) {
#pragma unroll
    for (int i = 0; i < 2; ++i) {
      const int li = (w * 2 + i) * 64 + l;       // 0..1023 chunk id
      const int rr = li >> 4, c = li & 15;
      async16(kb0 + (size_t)(kv0 + rr) * QKVW + ((c ^ (rr & 7)) << 3),
              (char*)kdst + (w * 2 + i) * 1024);
    }
  };
  auto stageV = [&](int kv0) {
#pragma unroll
    for (int i = 0; i < 2; ++i) {
      const int li = (w * 2 + i) * 64 + l;
      const int d = li >> 3, c = li & 7;
      async16(vb0 + (size_t)d * NS + kv0 + ((c ^ (d & 7)) << 3),
              (char*)Vt + (w * 2 + i) * 1024);
    }
  };

  stageK(Ks[0], 0);
  int cur = 0;
  // shuffle sources for the P exchange (same r, groups 2(g&1) and 2(g&1)+1)
  const int srcA = r + ((l & 16) << 1);
  const int srcB = srcA + 16;
  const bool hi = (l & 32) != 0;                 // g>>1

  for (int kvt = 0; kvt < nkv; ++kvt) {
    const int kv0 = kvt * 64;
    asm volatile("s_waitcnt vmcnt(0) lgkmcnt(0)" ::: "memory");
    __builtin_amdgcn_s_barrier();               // K[cur] landed; Vt reads done
    __builtin_amdgcn_sched_barrier(0);

    stageV(kv0);                                // 2 async16 / thread
    const bool haveNext = (kvt + 1 < nkv);
    if (haveNext) stageK(Ks[cur ^ 1], kv0 + 64);

    // wave fully below this KV tile? (rows all masked) -> skip compute
    const bool active = kv0 <= q0 + w * 16 + 15;

    union { u32 wrd[4]; bf16x8 v; } pf[2];
    if (active) {
      // ---- QK^T swapped: sacc[n] = S^T[key=n*16+4g+j][qrow=r] ----
      f32x4 sacc[4] = {};
      const char* ksB = (const char*)Ks[cur];
      __builtin_amdgcn_s_setprio(1);
#pragma unroll
      for (int n = 0; n < 4; ++n) {
        const int key = n * 16 + r;
        const int sw = (key & 7) << 4;
#pragma unroll
        for (int ks = 0; ks < 4; ++ks) {
          bf16x8 kf = *(const bf16x8*)(ksB + key * 256 + ((ks * 64 + g * 16) ^ sw));
          sacc[n] = __builtin_amdgcn_mfma_f32_16x16x32_bf16(kf, qf[ks], sacc[n], 0, 0, 0);
        }
      }
      __builtin_amdgcn_s_setprio(0);
      // ---- causal mask (last two tiles of this q-block) ----
      if (kvt >= 2 * qt) {
#pragma unroll
        for (int n = 0; n < 4; ++n) {
          const int key_g = kv0 + n * 16 + g * 4;
#pragma unroll
          for (int j = 0; j < 4; ++j)
            if (key_g + j > qrow) sacc[n][j] = -1e30f;
        }
      }
      // ---- per-lane online softmax (exp2 domain), T13 defer-rescale ----
      float mx = fmaxf(fmaxf(sacc[0][0], sacc[0][1]), fmaxf(sacc[0][2], sacc[0][3]));
#pragma unroll
      for (int n = 1; n < 4; ++n)
        mx = fmaxf(mx, fmaxf(fmaxf(sacc[n][0], sacc[n][1]), fmaxf(sacc[n][2], sacc[n][3])));
      mx = fmaxf(mx, __shfl_xor(mx, 16, 64));
      mx = fmaxf(mx, __shfl_xor(mx, 32, 64));
      if (!__all(mx <= mrun + 8.0f)) {          // rescale only when max grows
        const float mnew = fmaxf(mrun, mx);
        const float scale = exp2f(mrun - mnew);
        mrun = mnew;
        lrun *= scale;
#pragma unroll
        for (int dt = 0; dt < 8; ++dt) oacc[dt] *= scale;
      }
      float sum = 0.f;
#pragma unroll
      for (int n = 0; n < 4; ++n)
#pragma unroll
        for (int j = 0; j < 4; ++j) {
          float p = exp2f(sacc[n][j] - mrun);   // bounded by 2^8
          sacc[n][j] = p;
          sum += p;
        }
      sum += __shfl_xor(sum, 16, 64);
      sum += __shfl_xor(sum, 32, 64);
      lrun += sum;

      // ---- pack P to bf16 pairs, exchange to PV B-fragments in-register ----
      u32 pk[4][2];
#pragma unroll
      for (int n = 0; n < 4; ++n) {
        pk[n][0] = pack2bf(sacc[n][0], sacc[n][1]);
        pk[n][1] = pack2bf(sacc[n][2], sacc[n][3]);
      }
#pragma unroll
      for (int ks2 = 0; ks2 < 2; ++ks2) {
        const int n0 = 2 * ks2, n1 = 2 * ks2 + 1;
#pragma unroll
        for (int hh2 = 0; hh2 < 2; ++hh2) {
          u32 a0 = (u32)__shfl((int)pk[n0][hh2], srcA, 64);
          u32 a1 = (u32)__shfl((int)pk[n1][hh2], srcA, 64);
          pf[ks2].wrd[hh2] = hi ? a1 : a0;
          u32 b0 = (u32)__shfl((int)pk[n0][hh2], srcB, 64);
          u32 b1 = (u32)__shfl((int)pk[n1][hh2], srcB, 64);
          pf[ks2].wrd[2 + hh2] = hi ? b1 : b0;
        }
      }
    }

    // ---- PV swapped: oacc[dt] += V^T[d-block dt] x P ----
    if (haveNext) asm volatile("s_waitcnt vmcnt(2)" ::: "memory");
    else          asm volatile("s_waitcnt vmcnt(0)" ::: "memory");
    __builtin_amdgcn_s_barrier();               // V[cur] landed everywhere
    __builtin_amdgcn_sched_barrier(0);
    if (active) {
      const char* vtB = (const char*)Vt;
      __builtin_amdgcn_s_setprio(1);
#pragma unroll
      for (int ks2 = 0; ks2 < 2; ++ks2) {
#pragma unroll
        for (int dt = 0; dt < 8; ++dt) {
          const int d = dt * 16 + r;
          bf16x8 vf = *(const bf16x8*)(vtB + d * 128 +
                                       ((ks2 * 64 + g * 16) ^ ((d & 7) << 4)));
          oacc[dt] = __builtin_amdgcn_mfma_f32_16x16x32_bf16(vf, pf[ks2].v, oacc[dt], 0, 0, 0);
        }
      }
      __builtin_amdgcn_s_setprio(0);
    }
    cur ^= 1;
  }

  // ---- epilogue: O^T -> Oh[token][h*128+d], packed 8B stores ----
  const float inv = 1.f / lrun;
  const size_t obase = (size_t)(b * NS + qrow) * QSZ + h * HD;
#pragma unroll
  for (int dt = 0; dt < 8; ++dt) {
    uint2 r2;
    r2.x = pack2bf(oacc[dt][0] * inv, oacc[dt][1] * inv);
    r2.y = pack2bf(oacc[dt][2] * inv, oacc[dt][3] * inv);
    *(uint2*)(Oh + obase + dt * 16 + 4 * g) = r2;
  }
}

// -------------------------------------------------------------------------------
extern "C" void kernel_launch(void* const* d_in, const int* in_sizes, int n_in,
                              void* d_out, int out_size, void* d_ws, size_t ws_size,
                              hipStream_t stream) {
  const int* positions = (const int*)d_in[0];
  const float* hidden = (const float*)d_in[1];
  const float* w_qkv = (const float*)d_in[2];
  const float* b_qkv = (const float*)d_in[3];
  const float* w_o = (const float*)d_in[4];
  float* out = (float*)d_out;

  char* ws = (char*)d_ws;
  const size_t XB_OFF = 0;                           // 29,360,128 B (later reused by WoT)
  const size_t WQT_OFF = 29360128;                   // 33,030,144 B (later reused by Oh)
  const size_t QKV_OFF = WQT_OFF + 33030144;         // 37,748,736 B
  const size_t CS_OFF = QKV_OFF + 37748736;          // 1,048,576 B
  const size_t SN_OFF = CS_OFF + 1048576;            // 1,048,576 B
  const size_t WS_NEED = SN_OFF + 1048576;           // ~102.2 MB (known-safe)
  if (ws_size < WS_NEED) return;

  u16* Xb = (u16*)(ws + XB_OFF);
  u16* WoT = (u16*)(ws + XB_OFF);    // alias: after GEMM1 consumed Xb
  u16* WqT = (u16*)(ws + WQT_OFF);
  u16* Oh = (u16*)(ws + WQT_OFF);    // alias: after GEMM1 consumed WqT
  u16* qkvb = (u16*)(ws + QKV_OFF);
  float* cs = (float*)(ws + CS_OFF);
  float* sn = (float*)(ws + SN_OFF);
  // V^T scratch lives in d_out (4MB of 56MB); GEMM2 fully overwrites d_out later.
  u16* vtg = (u16*)d_out;

  cast_f32_bf16<<<14336, 256, 0, stream>>>(hidden, Xb);
  transpose_cast<<<dim3(QKVW / 32, HIDDEN_DIM / 32), 256, 0, stream>>>(w_qkv, WqT, HIDDEN_DIM, QKVW);
  rope_table<<<(NTOK * 64) / 256, 256, 0, stream>>>(positions, cs, sn);

  // QKV projection (+bias); V columns written transposed to vtg
  gemm128<true, true, true><<<(QKVW / 128) * (NTOK / 128), 256, 0, stream>>>(
      Xb, WqT, b_qkv, qkvb, nullptr, vtg, NTOK, QKVW, HIDDEN_DIM);

  rope_kernel<<<(NTOK * 32) / 4, 256, 0, stream>>>(qkvb, cs, sn);

  transpose_cast<<<dim3(HIDDEN_DIM / 32, QSZ / 32), 256, 0, stream>>>(w_o, WoT, QSZ, HIDDEN_DIM);

  attn_kernel<<<NB * NHEAD * (NS / 128), 512, 0, stream>>>(qkvb, vtg, Oh);

  gemm128<false, false, false><<<(HIDDEN_DIM / 128) * (NTOK / 128), 256, 0, stream>>>(
      Oh, WoT, nullptr, nullptr, out, nullptr, NTOK, HIDDEN_DIM, QSZ);
}

// Round 6
// 575.941 us; speedup vs baseline: 1.8727x; 1.1772x over previous
//
#include <hip/hip_runtime.h>

typedef unsigned short u16;
typedef unsigned int u32;
typedef __bf16 bf16x8 __attribute__((ext_vector_type(8)));
typedef float f32x4 __attribute__((ext_vector_type(4)));

#define NHEAD 28
#define NKVH 4
#define HD 128
#define NB 2
#define NS 2048
#define NTOK 4096
#define HIDDEN_DIM 3584
#define QKVW 4608
#define QSZ 3584
#define KOFF 3584
#define VOFF 4096
// QSCALE * log2(e): softmax runs in exp2 domain (v_exp_f32 is 2^x)
#define QSCALE_L2E 0.12751744f

__device__ __forceinline__ float bf2f(u16 u) {
  u32 x = ((u32)u) << 16; float f; __builtin_memcpy(&f, &x, 4); return f;
}
__device__ __forceinline__ u16 f2bf(float f) {
  u32 x; __builtin_memcpy(&x, &f, 4);
  x += 0x7FFFu + ((x >> 16) & 1u);
  return (u16)(x >> 16);
}
__device__ __forceinline__ u32 pack2bf(float a, float b) {
  return (u32)f2bf(a) | ((u32)f2bf(b) << 16);
}
__device__ __forceinline__ void async16(const void* g, void* lds) {
  __builtin_amdgcn_global_load_lds((const __attribute__((address_space(1))) void*)g,
                                   (__attribute__((address_space(3))) void*)lds,
                                   16, 0, 0);
}

#define SB __builtin_amdgcn_sched_barrier(0)
#define BAR do { SB; __builtin_amdgcn_s_barrier(); SB; } while (0)

// ---------------- elementwise f32 -> bf16 cast (4 elems/thread) ----------------
__global__ void cast_f32_bf16(const float* __restrict__ in, u16* __restrict__ out) {
  int i = (blockIdx.x * 256 + threadIdx.x) * 4;
  float4 v = *(const float4*)(in + i);
  u32 p0 = (u32)f2bf(v.x) | ((u32)f2bf(v.y) << 16);
  u32 p1 = (u32)f2bf(v.z) | ((u32)f2bf(v.w) << 16);
  uint2 r; r.x = p0; r.y = p1;
  *(uint2*)(out + i) = r;
}

// ------------- tiled transpose + cast: in f32 [R][C] -> out bf16 [C][R] --------
__global__ void transpose_cast(const float* __restrict__ in, u16* __restrict__ out,
                               int R, int C) {
  __shared__ float tile[32][33];
  int tx = threadIdx.x & 31, ty = threadIdx.x >> 5;   // 32 x 8
  int c0 = blockIdx.x * 32, r0 = blockIdx.y * 32;
#pragma unroll
  for (int i = 0; i < 32; i += 8)
    tile[ty + i][tx] = in[(size_t)(r0 + ty + i) * C + c0 + tx];
  __syncthreads();
#pragma unroll
  for (int i = 0; i < 32; i += 8)
    out[(size_t)(c0 + ty + i) * R + r0 + tx] = f2bf(tile[tx][ty + i]);
}

// ---------------- rope cos/sin table: [NTOK][64] each --------------------------
__global__ void rope_table(const int* __restrict__ positions,
                           float* __restrict__ cs, float* __restrict__ sn) {
  int idx = blockIdx.x * 256 + threadIdx.x;   // NTOK*64
  int t = idx >> 6, i = idx & 63;
  float p = (float)positions[t];
  float inv = expf(-(float)i * (13.815510557964274f / 64.f));
  float a = p * inv;
  cs[idx] = cosf(a);
  sn[idx] = sinf(a);
}

// --------- in-place RoPE on qkv (q scaled by D^-0.5 * log2e for exp2-softmax) --
__global__ void rope_kernel(u16* __restrict__ qkv, const float* __restrict__ cs,
                            const float* __restrict__ sn) {
  int w = threadIdx.x >> 6, l = threadIdx.x & 63;
  int rid = blockIdx.x * 4 + w;          // NTOK * 32 head-rows
  int t = rid >> 5, hh = rid & 31;
  size_t base = (size_t)t * QKVW + (hh < NHEAD ? hh * HD : KOFF + (hh - NHEAD) * HD);
  float x1 = bf2f(qkv[base + l]), x2 = bf2f(qkv[base + l + 64]);
  float c = cs[t * 64 + l], s = sn[t * 64 + l];
  float y1 = x1 * c - x2 * s;
  float y2 = x2 * c + x1 * s;
  if (hh < NHEAD) { y1 *= QSCALE_L2E; y2 *= QSCALE_L2E; }
  qkv[base + l] = f2bf(y1);
  qkv[base + l + 64] = f2bf(y2);
}

// ---------------- 256x256 8-phase MFMA GEMM (m201-class template) --------------
// A [M][K] bf16, Bt [N][K] bf16. BK=64, 8 waves (2M x 4N), per-wave C = 128x64.
// LDS: 2 slots x (A 256x64 + B 256x64) = 128 KiB. Per K-tile: 4 quadrant phases
// of 16 MFMA; one 16KB half staged per phase; counted vmcnt(4) once per tile.
// T2 swizzle slot^=row&7 (write-side pre-swizzled source, read-side XOR).
// VSPLIT: V-column tiles (col0>=VOFF) write TRANSPOSED to vtg.
template <bool OUT_BF16, bool HAS_BIAS, bool VSPLIT>
__global__ __launch_bounds__(512, 2) void gemm256(
    const u16* __restrict__ A, const u16* __restrict__ Bt,
    const float* __restrict__ bias, u16* __restrict__ outb,
    float* __restrict__ outf, u16* __restrict__ vtg, int M, int N, int K) {
  __shared__ __align__(16) u16 Al[2][256 * 64];   // 64 KiB
  __shared__ __align__(16) u16 Bl[2][256 * 64];   // 64 KiB
  const int tid = threadIdx.x;
  const int l = tid & 63, w = tid >> 6;
  const int g = l >> 4, r = l & 15;
  const int wm = w >> 2, wn = w & 3;
  const int nbx = N >> 8;
  const int cpx = (int)gridDim.x >> 3;            // grid % 8 == 0
  const int bid = ((int)blockIdx.x & 7) * cpx + ((int)blockIdx.x >> 3);
  const int bx = bid % nbx, by = bid / nbx;
  const int row0 = by * 256, col0 = bx * 256;
  const int NT = K >> 6;

  f32x4 acc[8][4] = {};
  bf16x8 af[4][2];        // A-frags: 4 row-frags x 2 k-halves (one rh quadrant)
  bf16x8 bfr[2][2][2];    // B-frags: [ch][fc][kk] — both col-quadrants held

  // stage one 16KB half (128 rows x 64 k) of A or B for k-tile t
  auto stageU = [&](const u16* mb, int base0, char* ldsMat, int h, int t) {
#pragma unroll
    for (int q = 0; q < 2; ++q) {
      const int idx = q * 512 + tid;              // 0..1023 16B-chunks
      const int rho = h * 128 + (idx >> 3);       // row within 256-row tile
      const int sl = (idx & 7) ^ (rho & 7);       // pre-swizzled source slot
      async16(mb + (size_t)(base0 + rho) * K + t * 64 + sl * 8,
              ldsMat + (size_t)(t & 1) * 32768 + h * 16384 + idx * 16);
    }
  };

#define READ_A(s, rh)                                                           \
  _Pragma("unroll") for (int fr = 0; fr < 4; ++fr) {                            \
    const int row_ = (rh) * 128 + wm * 64 + fr * 16 + r;                        \
    _Pragma("unroll") for (int kk = 0; kk < 2; ++kk) {                          \
      const int sl_ = (kk * 4 + g) ^ (row_ & 7);                                \
      af[fr][kk] = *(const bf16x8*)((const char*)Al + (s) * 32768 +             \
                                    row_ * 128 + sl_ * 16);                     \
    }                                                                           \
  }
#define READ_B(s, ch)                                                           \
  _Pragma("unroll") for (int fc = 0; fc < 2; ++fc) {                            \
    const int col_ = (ch) * 128 + wn * 32 + fc * 16 + r;                        \
    _Pragma("unroll") for (int kk = 0; kk < 2; ++kk) {                          \
      const int sl_ = (kk * 4 + g) ^ (col_ & 7);                                \
      bfr[ch][fc][kk] = *(const bf16x8*)((const char*)Bl + (s) * 32768 +        \
                                         col_ * 128 + sl_ * 16);                \
    }                                                                           \
  }
#define MFMA_Q(rh, ch)                                                          \
  __builtin_amdgcn_s_setprio(1);                                                \
  _Pragma("unroll") for (int fr = 0; fr < 4; ++fr)                              \
  _Pragma("unroll") for (int fc = 0; fc < 2; ++fc)                              \
  _Pragma("unroll") for (int kk = 0; kk < 2; ++kk)                              \
    acc[(rh) * 4 + fr][(ch) * 2 + fc] = __builtin_amdgcn_mfma_f32_16x16x32_bf16( \
        af[fr][kk], bfr[ch][fc][kk], acc[(rh) * 4 + fr][(ch) * 2 + fc], 0, 0, 0);\
  __builtin_amdgcn_s_setprio(0);

  // ---- prologue: tile0 full + tile1 A0,B0; counted drain leaves 4 in flight ---
  stageU(A, row0, (char*)Al, 0, 0); stageU(A, row0, (char*)Al, 1, 0);
  stageU(Bt, col0, (char*)Bl, 0, 0); stageU(Bt, col0, (char*)Bl, 1, 0);
  stageU(A, row0, (char*)Al, 0, 1); stageU(Bt, col0, (char*)Bl, 0, 1);
  SB; asm volatile("s_waitcnt vmcnt(4)" ::: "memory");
  BAR;

  for (int t = 0; t < NT; ++t) {
    const int s = t & 1;
    // phase 1: quad(rh0,ch0); stage A-h1(t+1)  [dead: slot^1 A-h1 since prev ph4]
    READ_A(s, 0); READ_B(s, 0);
    if (t + 1 < NT) stageU(A, row0, (char*)Al, 1, t + 1);
    BAR; MFMA_Q(0, 0); BAR;
    // phase 2: quad(rh0,ch1); stage B-h1(t+1)
    READ_B(s, 1);
    if (t + 1 < NT) stageU(Bt, col0, (char*)Bl, 1, t + 1);
    BAR; MFMA_Q(0, 1); BAR;
    // phase 3: quad(rh1,ch0); stage A-h0(t+2)  [this slot's A-h0 dead after ph2]
    READ_A(s, 1);
    if (t + 2 < NT) stageU(A, row0, (char*)Al, 0, t + 2);
    BAR; MFMA_Q(1, 0); BAR;
    // phase 4: quad(rh1,ch1); stage B-h0(t+2)  [this slot's B-h0 dead after ph3]
    if (t + 2 < NT) stageU(Bt, col0, (char*)Bl, 0, t + 2);
    BAR; MFMA_Q(1, 1);
    if (t < NT - 2)        { SB; asm volatile("s_waitcnt vmcnt(4)" ::: "memory"); }
    else if (t == NT - 2)  { SB; asm volatile("s_waitcnt vmcnt(0)" ::: "memory"); }
    BAR;
  }
  SB; asm volatile("s_waitcnt vmcnt(0)" ::: "memory");

  // ---- epilogue ----
  if (VSPLIT && col0 >= VOFF) {
    // transposed V: vtg[(b*NKVH+kvh)*HD + d][s], 4 consecutive s per write
#pragma unroll
    for (int m = 0; m < 8; ++m) {
      const int row = row0 + (m >> 2) * 128 + wm * 64 + (m & 3) * 16 + g * 4;
      const int bb_ = row >> 11, sidx = row & 2047;
#pragma unroll
      for (int n = 0; n < 4; ++n) {
        const int col = col0 + (n >> 1) * 128 + wn * 32 + (n & 1) * 16 + r;
        const int kvh = (col - VOFF) >> 7, d = (col - VOFF) & 127;
        const float bv = HAS_BIAS ? bias[col] : 0.f;
        uint2 r2;
        r2.x = pack2bf(acc[m][n][0] + bv, acc[m][n][1] + bv);
        r2.y = pack2bf(acc[m][n][2] + bv, acc[m][n][3] + bv);
        *(uint2*)(vtg + ((size_t)((bb_ * NKVH + kvh) * HD + d)) * NS + sidx) = r2;
      }
    }
    return;
  }

#pragma unroll
  for (int m = 0; m < 8; ++m) {
    const int row = row0 + (m >> 2) * 128 + wm * 64 + (m & 3) * 16 + g * 4;
#pragma unroll
    for (int n = 0; n < 4; ++n) {
      const int col = col0 + (n >> 1) * 128 + wn * 32 + (n & 1) * 16 + r;
      const float bb = HAS_BIAS ? bias[col] : 0.f;
#pragma unroll
      for (int j = 0; j < 4; ++j) {
        float v = acc[m][n][j] + bb;
        if (OUT_BF16) outb[(size_t)(row + j) * N + col] = f2bf(v);
        else          outf[(size_t)(row + j) * N + col] = v;
      }
    }
  }
}

// ---------------- causal GQA flash attention (swapped-operand form) ------------
// 8 waves, QBLK=128 (16 q-rows/wave), KVBLK=64. QK^T as mfma(K,Q) -> S^T
// (col = q-row): per-lane softmax + 2 shuffles. PV as mfma(V^T,P) -> O^T.
// P exchanged in-register. K dbuf + V single-buf via global_load_lds, counted
// vmcnt. T13 defer-rescale; fully-masked waves skip compute; T5 setprio.
__global__ __launch_bounds__(512) void attn_kernel(const u16* __restrict__ qkv,
                                                   const u16* __restrict__ vtg,
                                                   u16* __restrict__ Oh) {
  __shared__ __align__(16) u16 Ks[2][64 * 128];   // [key][d] swizzled, 16KB each
  __shared__ __align__(16) u16 Vt[128 * 64];      // [d][key] swizzled, 16KB
  const int tid = threadIdx.x, l = tid & 63, w = tid >> 6;   // w 0..7
  const int g = l >> 4, r = l & 15;
  const int bidx = blockIdx.x;
  const int qt = 15 - (bidx & 15);               // heavy q-tiles first
  const int bh = bidx >> 4;
  const int h = bh % NHEAD, b = bh / NHEAD;
  const int kvh = h / 7;
  const int q0 = qt * 128;

  // Q fragment (B-frag role: col = r = q-row, k = ks*32 + g*8 + i)
  const int qrow = q0 + w * 16 + r;
  const size_t qbase = (size_t)(b * NS + qrow) * QKVW + h * HD;
  bf16x8 qf[4];
#pragma unroll
  for (int ks = 0; ks < 4; ++ks)
    qf[ks] = *(const bf16x8*)(qkv + qbase + ks * 32 + g * 8);

  const u16* kb0 = qkv + (size_t)(b * NS) * QKVW + KOFF + kvh * HD;
  const u16* vb0 = vtg + (size_t)((b * NKVH + kvh) * HD) * NS;

  f32x4 oacc[8] = {};           // O^T: oacc[dt][j] = O[qrow=r][d=dt*16+4g+j]
  float mrun = -1e30f, lrun = 0.f;

  const int nkv = 2 * qt + 2;

  auto stageK = [&](u16* kdst, int kv0) {
#pragma unroll
    for (int i = 0; i < 2; ++i) {
      const int li = (w * 2 + i) * 64 + l;       // 0..1023 chunk id
      const int rr = li >> 4, c = li & 15;
      async16(kb0 + (size_t)(kv0 + rr) * QKVW + ((c ^ (rr & 7)) << 3),
              (char*)kdst + (w * 2 + i) * 1024);
    }
  };
  auto stageV = [&](int kv0) {
#pragma unroll
    for (int i = 0; i < 2; ++i) {
      const int li = (w * 2 + i) * 64 + l;
      const int d = li >> 3, c = li & 7;
      async16(vb0 + (size_t)d * NS + kv0 + ((c ^ (d & 7)) << 3),
              (char*)Vt + (w * 2 + i) * 1024);
    }
  };

  stageK(Ks[0], 0);
  int cur = 0;
  // shuffle sources for the P exchange (same r, groups 2(g&1) and 2(g&1)+1)
  const int srcA = r + ((l & 16) << 1);
  const int srcB = srcA + 16;
  const bool hi = (l & 32) != 0;                 // g>>1

  for (int kvt = 0; kvt < nkv; ++kvt) {
    const int kv0 = kvt * 64;
    asm volatile("s_waitcnt vmcnt(0) lgkmcnt(0)" ::: "memory");
    __builtin_amdgcn_s_barrier();               // K[cur] landed; Vt reads done
    __builtin_amdgcn_sched_barrier(0);

    stageV(kv0);                                // 2 async16 / thread
    const bool haveNext = (kvt + 1 < nkv);
    if (haveNext) stageK(Ks[cur ^ 1], kv0 + 64);

    // wave fully below this KV tile? (rows all masked) -> skip compute
    const bool active = kv0 <= q0 + w * 16 + 15;

    union { u32 wrd[4]; bf16x8 v; } pf[2];
    if (active) {
      // ---- QK^T swapped: sacc[n] = S^T[key=n*16+4g+j][qrow=r] ----
      f32x4 sacc[4] = {};
      const char* ksB = (const char*)Ks[cur];
      __builtin_amdgcn_s_setprio(1);
#pragma unroll
      for (int n = 0; n < 4; ++n) {
        const int key = n * 16 + r;
        const int sw = (key & 7) << 4;
#pragma unroll
        for (int ks = 0; ks < 4; ++ks) {
          bf16x8 kf = *(const bf16x8*)(ksB + key * 256 + ((ks * 64 + g * 16) ^ sw));
          sacc[n] = __builtin_amdgcn_mfma_f32_16x16x32_bf16(kf, qf[ks], sacc[n], 0, 0, 0);
        }
      }
      __builtin_amdgcn_s_setprio(0);
      // ---- causal mask (last two tiles of this q-block) ----
      if (kvt >= 2 * qt) {
#pragma unroll
        for (int n = 0; n < 4; ++n) {
          const int key_g = kv0 + n * 16 + g * 4;
#pragma unroll
          for (int j = 0; j < 4; ++j)
            if (key_g + j > qrow) sacc[n][j] = -1e30f;
        }
      }
      // ---- per-lane online softmax (exp2 domain), T13 defer-rescale ----
      float mx = fmaxf(fmaxf(sacc[0][0], sacc[0][1]), fmaxf(sacc[0][2], sacc[0][3]));
#pragma unroll
      for (int n = 1; n < 4; ++n)
        mx = fmaxf(mx, fmaxf(fmaxf(sacc[n][0], sacc[n][1]), fmaxf(sacc[n][2], sacc[n][3])));
      mx = fmaxf(mx, __shfl_xor(mx, 16, 64));
      mx = fmaxf(mx, __shfl_xor(mx, 32, 64));
      if (!__all(mx <= mrun + 8.0f)) {          // rescale only when max grows
        const float mnew = fmaxf(mrun, mx);
        const float scale = exp2f(mrun - mnew);
        mrun = mnew;
        lrun *= scale;
#pragma unroll
        for (int dt = 0; dt < 8; ++dt) oacc[dt] *= scale;
      }
      float sum = 0.f;
#pragma unroll
      for (int n = 0; n < 4; ++n)
#pragma unroll
        for (int j = 0; j < 4; ++j) {
          float p = exp2f(sacc[n][j] - mrun);   // bounded by 2^8
          sacc[n][j] = p;
          sum += p;
        }
      sum += __shfl_xor(sum, 16, 64);
      sum += __shfl_xor(sum, 32, 64);
      lrun += sum;

      // ---- pack P to bf16 pairs, exchange to PV B-fragments in-register ----
      u32 pk[4][2];
#pragma unroll
      for (int n = 0; n < 4; ++n) {
        pk[n][0] = pack2bf(sacc[n][0], sacc[n][1]);
        pk[n][1] = pack2bf(sacc[n][2], sacc[n][3]);
      }
#pragma unroll
      for (int ks2 = 0; ks2 < 2; ++ks2) {
        const int n0 = 2 * ks2, n1 = 2 * ks2 + 1;
#pragma unroll
        for (int hh2 = 0; hh2 < 2; ++hh2) {
          u32 a0 = (u32)__shfl((int)pk[n0][hh2], srcA, 64);
          u32 a1 = (u32)__shfl((int)pk[n1][hh2], srcA, 64);
          pf[ks2].wrd[hh2] = hi ? a1 : a0;
          u32 b0 = (u32)__shfl((int)pk[n0][hh2], srcB, 64);
          u32 b1 = (u32)__shfl((int)pk[n1][hh2], srcB, 64);
          pf[ks2].wrd[2 + hh2] = hi ? b1 : b0;
        }
      }
    }

    // ---- PV swapped: oacc[dt] += V^T[d-block dt] x P ----
    if (haveNext) asm volatile("s_waitcnt vmcnt(2)" ::: "memory");
    else          asm volatile("s_waitcnt vmcnt(0)" ::: "memory");
    __builtin_amdgcn_s_barrier();               // V[cur] landed everywhere
    __builtin_amdgcn_sched_barrier(0);
    if (active) {
      const char* vtB = (const char*)Vt;
      __builtin_amdgcn_s_setprio(1);
#pragma unroll
      for (int ks2 = 0; ks2 < 2; ++ks2) {
#pragma unroll
        for (int dt = 0; dt < 8; ++dt) {
          const int d = dt * 16 + r;
          bf16x8 vf = *(const bf16x8*)(vtB + d * 128 +
                                       ((ks2 * 64 + g * 16) ^ ((d & 7) << 4)));
          oacc[dt] = __builtin_amdgcn_mfma_f32_16x16x32_bf16(vf, pf[ks2].v, oacc[dt], 0, 0, 0);
        }
      }
      __builtin_amdgcn_s_setprio(0);
    }
    cur ^= 1;
  }

  // ---- epilogue: O^T -> Oh[token][h*128+d], packed 8B stores ----
  const float inv = 1.f / lrun;
  const size_t obase = (size_t)(b * NS + qrow) * QSZ + h * HD;
#pragma unroll
  for (int dt = 0; dt < 8; ++dt) {
    uint2 r2;
    r2.x = pack2bf(oacc[dt][0] * inv, oacc[dt][1] * inv);
    r2.y = pack2bf(oacc[dt][2] * inv, oacc[dt][3] * inv);
    *(uint2*)(Oh + obase + dt * 16 + 4 * g) = r2;
  }
}

// -------------------------------------------------------------------------------
extern "C" void kernel_launch(void* const* d_in, const int* in_sizes, int n_in,
                              void* d_out, int out_size, void* d_ws, size_t ws_size,
                              hipStream_t stream) {
  const int* positions = (const int*)d_in[0];
  const float* hidden = (const float*)d_in[1];
  const float* w_qkv = (const float*)d_in[2];
  const float* b_qkv = (const float*)d_in[3];
  const float* w_o = (const float*)d_in[4];
  float* out = (float*)d_out;

  char* ws = (char*)d_ws;
  const size_t XB_OFF = 0;                           // 29,360,128 B (later reused by WoT)
  const size_t WQT_OFF = 29360128;                   // 33,030,144 B (later reused by Oh)
  const size_t QKV_OFF = WQT_OFF + 33030144;         // 37,748,736 B
  const size_t CS_OFF = QKV_OFF + 37748736;          // 1,048,576 B
  const size_t SN_OFF = CS_OFF + 1048576;            // 1,048,576 B
  const size_t WS_NEED = SN_OFF + 1048576;           // ~102.2 MB (known-safe)
  if (ws_size < WS_NEED) return;

  u16* Xb = (u16*)(ws + XB_OFF);
  u16* WoT = (u16*)(ws + XB_OFF);    // alias: after GEMM1 consumed Xb
  u16* WqT = (u16*)(ws + WQT_OFF);
  u16* Oh = (u16*)(ws + WQT_OFF);    // alias: after GEMM1 consumed WqT
  u16* qkvb = (u16*)(ws + QKV_OFF);
  float* cs = (float*)(ws + CS_OFF);
  float* sn = (float*)(ws + SN_OFF);
  // V^T scratch lives in d_out (4MB of 56MB); GEMM2 fully overwrites d_out later.
  u16* vtg = (u16*)d_out;

  cast_f32_bf16<<<14336, 256, 0, stream>>>(hidden, Xb);
  transpose_cast<<<dim3(QKVW / 32, HIDDEN_DIM / 32), 256, 0, stream>>>(w_qkv, WqT, HIDDEN_DIM, QKVW);
  rope_table<<<(NTOK * 64) / 256, 256, 0, stream>>>(positions, cs, sn);

  // QKV projection (+bias); V columns written transposed to vtg
  gemm256<true, true, true><<<(QKVW / 256) * (NTOK / 256), 512, 0, stream>>>(
      Xb, WqT, b_qkv, qkvb, nullptr, vtg, NTOK, QKVW, HIDDEN_DIM);

  rope_kernel<<<(NTOK * 32) / 4, 256, 0, stream>>>(qkvb, cs, sn);

  transpose_cast<<<dim3(HIDDEN_DIM / 32, QSZ / 32), 256, 0, stream>>>(w_o, WoT, QSZ, HIDDEN_DIM);

  attn_kernel<<<NB * NHEAD * (NS / 128), 512, 0, stream>>>(qkvb, vtg, Oh);

  gemm256<false, false, false><<<(HIDDEN_DIM / 256) * (NTOK / 256), 512, 0, stream>>>(
      Oh, WoT, nullptr, nullptr, out, nullptr, NTOK, HIDDEN_DIM, QSZ);
}